// Round 1
// baseline (1772.995 us; speedup 1.0000x reference)
//
#include <hip/hip_runtime.h>
#include <hip/hip_bf16.h>
#include <stdint.h>

#define NN 32
#define CC 64
#define TTOT 256
#define VV 25
#define NS 3
constexpr int TV  = TTOT * VV;            // 6400
constexpr int CTV = CC * TV;              // 409600
constexpr size_t PLANE = (size_t)NN * CTV; // 13107200

typedef unsigned short ushort_t;
using short8 = __attribute__((ext_vector_type(8))) short;
using f32x4  = __attribute__((ext_vector_type(4))) float;

static __device__ __forceinline__ ushort_t f2bf(float f) {
  union { float f; uint32_t u; } v; v.f = f;
  return (ushort_t)((v.u + 0x7FFFu + ((v.u >> 16) & 1u)) >> 16);
}
static __device__ __forceinline__ float bf2f(ushort_t h) {
  union { uint32_t u; float f; } v; v.u = ((uint32_t)h) << 16;
  return v.f;
}
// element offset into a [row][128] bf16 tile, XOR-swizzled (byte ^= (row&7)<<4)
static __device__ __forceinline__ int SWZ(int row, int k) {
  return ((row << 7) + k) ^ ((row & 7) << 3);
}
static __device__ __forceinline__ f32x4 mfma16(short8 a, short8 b, f32x4 c) {
  return __builtin_amdgcn_mfma_f32_16x16x32_bf16(a, b, c, 0, 0, 0);
}

// ---------------------------------------------------------------------------
// K1: per (n, tc) with 4 t's: conv (MFMA) -> a,b in LDS -> Gram outer (fp32)
// Spart[3][32][64][25][25][2]
// ---------------------------------------------------------------------------
__global__ __launch_bounds__(256) void k1_spart(
    const float* __restrict__ xr, const float* __restrict__ xi,
    const float* __restrict__ Wa, const float* __restrict__ ba,
    const float* __restrict__ Wb, const float* __restrict__ bb,
    float* __restrict__ Spart)
{
  const int tc = blockIdx.x, n = blockIdx.y;
  const int tid = threadIdx.x, lane = tid & 63, wv = tid >> 6;
  __shared__ alignas(16) ushort_t zc[128 * 128]; // [pos2=t*32+v][c] swizzled
  __shared__ alignas(16) ushort_t wl[64 * 128];  // [row][c] swizzled
  __shared__ alignas(16) ushort_t ab[64 * 128];  // [row][pos2] plain

  // stage zc (v>=25 zero-padded)
  for (int e = tid; e < 128 * 128; e += 256) {
    int v = e & 31, t = (e >> 5) & 3, c = e >> 7;
    float val = 0.f;
    if (v < VV) {
      const float* src = (c < 64) ? xr : xi;
      val = src[(size_t)n * CTV + (c & 63) * TV + (tc * 4 + t) * VV + v];
    }
    zc[SWZ(t * 32 + v, c)] = f2bf(val);
  }
  __syncthreads();

  const int uo = tid / 7, vg = tid % 7; // outer mapping (175 active threads)

  for (int i = 0; i < NS; ++i) {
    // stage weights: rows 0..31 = Wa[i], 32..63 = Wb[i]
    for (int e = tid; e < 64 * 128; e += 256) {
      int c = e & 127, r = e >> 7;
      const float* w = (r < 32) ? (Wa + (size_t)(i * 32 + r) * 128)
                                : (Wb + (size_t)(i * 32 + (r - 32)) * 128);
      wl[SWZ(r, c)] = f2bf(w[c]);
    }
    __syncthreads();

    // conv: wave wv owns output rows [wv*16, wv*16+16)
    {
      const int mt = wv;
      const int arow = mt * 16 + (lane & 15);
      short8 afr[4];
#pragma unroll
      for (int ks = 0; ks < 4; ++ks)
        afr[ks] = *(const short8*)&wl[SWZ(arow, ks * 32 + ((lane >> 4) << 3))];
      float bias[4];
#pragma unroll
      for (int j = 0; j < 4; ++j) {
        int row = mt * 16 + ((lane >> 4) << 2) + j;
        bias[j] = (row < 32) ? ba[i * 32 + row] : bb[i * 32 + (row - 32)];
      }
      for (int nt = 0; nt < 8; ++nt) {
        f32x4 acc = {0.f, 0.f, 0.f, 0.f};
        const int brow = nt * 16 + (lane & 15);
#pragma unroll
        for (int ks = 0; ks < 4; ++ks) {
          short8 bfr = *(const short8*)&zc[SWZ(brow, ks * 32 + ((lane >> 4) << 3))];
          acc = mfma16(afr[ks], bfr, acc);
        }
#pragma unroll
        for (int j = 0; j < 4; ++j) {
          int row = mt * 16 + ((lane >> 4) << 2) + j;
          int col = nt * 16 + (lane & 15);
          ab[row * 128 + col] = f2bf(acc[j] + bias[j]);
        }
      }
    }
    __syncthreads();

    // Gram outer product (fp32): S[u][v] += a[it,t,u]*b[it,t,v] (complex)
    if (tid < 175) {
      float Sacc[8];
#pragma unroll
      for (int j = 0; j < 8; ++j) Sacc[j] = 0.f;
      for (int t = 0; t < 4; ++t) {
        const int pb = t * 32;
        for (int it = 0; it < 16; ++it) {
          float ar = bf2f(ab[it * 128 + pb + uo]);
          float ai = bf2f(ab[(16 + it) * 128 + pb + uo]);
          const ushort_t* bp = &ab[(32 + it) * 128 + pb + vg * 4];
          const ushort_t* cp = &ab[(48 + it) * 128 + pb + vg * 4];
#pragma unroll
          for (int j = 0; j < 4; ++j) {
            float br = bf2f(bp[j]), bi = bf2f(cp[j]);
            Sacc[j * 2]     += ar * br - ai * bi;
            Sacc[j * 2 + 1] += ar * bi + ai * br;
          }
        }
      }
#pragma unroll
      for (int j = 0; j < 4; ++j) {
        int v = vg * 4 + j;
        if (v < VV) {
          size_t idx = ((((size_t)i * NN + n) * 64 + tc) * 625 + uo * 25 + v) * 2;
          Spart[idx] = Sacc[j * 2];
          Spart[idx + 1] = Sacc[j * 2 + 1];
        }
      }
    }
    __syncthreads();
  }
}

// ---------------------------------------------------------------------------
// K2: reduce Spart over tc, /4096, complex softmax over u, + (A+PA)
// ---------------------------------------------------------------------------
__global__ __launch_bounds__(256) void k2_softmax(
    const float* __restrict__ Spart, const float* __restrict__ Aw,
    const float* __restrict__ PA, float* __restrict__ Sfin)
{
  const int i = blockIdx.x, n = blockIdx.y, tid = threadIdx.x;
  __shared__ float ez[625 * 2];
  __shared__ float den[25 * 2];
  for (int e = tid; e < 625; e += 256) {
    float sr = 0.f, si = 0.f;
    const float* p = Spart + (((size_t)i * NN + n) * 64 * 625 + e) * 2;
    for (int tcb = 0; tcb < 64; ++tcb) { sr += p[0]; si += p[1]; p += 625 * 2; }
    sr *= (1.f / 4096.f); si *= (1.f / 4096.f);
    float m = expf(sr);
    ez[e * 2] = m * cosf(si);
    ez[e * 2 + 1] = m * sinf(si);
  }
  __syncthreads();
  if (tid < 25) {
    float dr = 0.f, di = 0.f;
    for (int u = 0; u < 25; ++u) { dr += ez[(u * 25 + tid) * 2]; di += ez[(u * 25 + tid) * 2 + 1]; }
    float inv = 1.f / (dr * dr + di * di);
    den[tid * 2] = dr * inv; den[tid * 2 + 1] = -di * inv; // conj(d)/|d|^2
  }
  __syncthreads();
  for (int e = tid; e < 625; e += 256) {
    int v = e % 25;
    float er = ez[e * 2], ei = ez[e * 2 + 1];
    float dr = den[v * 2], di = den[v * 2 + 1];
    float outr = er * dr - ei * di + Aw[i * 625 + e] + PA[i * 625 + e];
    float outi = er * di + ei * dr;
    size_t o = (((size_t)i * NN + n) * 625 + e) * 2;
    Sfin[o] = outr; Sfin[o + 1] = outi;
  }
}

// ---------------------------------------------------------------------------
// K3: per (n, tc) with 2 t's: z = X2*S (MFMA, S hi/lo split), Wd conv (MFMA),
//     accumulate over i, write y into d_out, block-local BN partials.
// ---------------------------------------------------------------------------
__global__ __launch_bounds__(256) void k3_y(
    const float* __restrict__ xr, const float* __restrict__ xi,
    const float* __restrict__ Sfin, const float* __restrict__ Wd,
    const float* __restrict__ bd, float* __restrict__ out,
    float* __restrict__ bnpart)
{
  const int tc = blockIdx.x, n = blockIdx.y;
  const int tid = threadIdx.x, lane = tid & 63, wv = tid >> 6;
  __shared__ alignas(16) ushort_t zcA[16 * 64 * 8];   // prefrag [mt][lane][8]
  __shared__ alignas(16) ushort_t sfr[6 * 2 * 64 * 8]; // [combo][nt][lane][8]
  __shared__ alignas(16) ushort_t zbuf[64 * 128];      // [pos2][k] swizzled
  __shared__ alignas(16) ushort_t wdl[128 * 128];      // [row][k] swizzled
  __shared__ float stats[128 * 2];

  // stage zcA: rows m = (imag?128:0) + c*2 + t, k = u (u>=25 zero)
  for (int e = tid; e < 8192; e += 256) {
    int u = e & 31, t = (e >> 5) & 1, cj = e >> 6;
    float val = 0.f;
    if (u < VV) {
      const float* src = (cj < 64) ? xr : xi;
      val = src[(size_t)n * CTV + (cj & 63) * TV + (tc * 2 + t) * VV + u];
    }
    int mrow = ((cj < 64) ? 0 : 128) + ((cj & 63) << 1) + t;
    int off = ((mrow >> 4) * 64 + (mrow & 15) + ((u >> 3) << 4)) * 8 + (u & 7);
    zcA[off] = f2bf(val);
  }

  f32x4 acc[2][4];
#pragma unroll
  for (int a = 0; a < 2; ++a)
#pragma unroll
    for (int b = 0; b < 4; ++b) acc[a][b] = {0.f, 0.f, 0.f, 0.f};

  for (int i = 0; i < NS; ++i) {
    __syncthreads(); // zcA ready / zbuf,sfr,wdl WAR vs previous iteration

    // stage S fragments: combos {Srh,Srl,Sih,Sil,-Sih,-Sil}
    for (int e = tid; e < 6 * 2 * 64; e += 256) {
      int l = e & 63, nt = (e >> 6) & 1, m = e >> 7;
      int u0 = (l >> 4) << 3, v = nt * 16 + (l & 15);
      short8 pk;
#pragma unroll
      for (int j = 0; j < 8; ++j) {
        int u = u0 + j;
        float val = 0.f;
        if (u < VV && v < VV) {
          const float* sp = Sfin + (((size_t)i * NN + n) * 625 + u * 25 + v) * 2;
          float base = (m < 2) ? sp[0] : (m < 4) ? sp[1] : -sp[1];
          if (m & 1) { float hi = bf2f(f2bf(base)); val = base - hi; }
          else val = base;
        }
        pk[j] = (short)f2bf(val);
      }
      *(short8*)&sfr[e * 8] = pk;
    }
    // stage Wd[i] (direct copy of [128][128])
    for (int e = tid; e < 16384; e += 256) {
      int k = e & 127, r = e >> 7;
      wdl[SWZ(r, k)] = f2bf(Wd[(size_t)i * 16384 + e]);
    }
    __syncthreads();

    // phase A: z = X2 * S  (complex via real MFMAs, hi+lo S)
    {
      short8 bfrag[6][2];
#pragma unroll
      for (int m = 0; m < 6; ++m)
#pragma unroll
        for (int nt = 0; nt < 2; ++nt)
          bfrag[m][nt] = *(const short8*)&sfr[((m * 2 + nt) * 64 + lane) * 8];
#pragma unroll
      for (int mtl = 0; mtl < 2; ++mtl) {
        int mt = wv * 2 + mtl;
        short8 Ar = *(const short8*)&zcA[(mt * 64 + lane) * 8];
        short8 Ai = *(const short8*)&zcA[((mt + 8) * 64 + lane) * 8];
#pragma unroll
        for (int nt = 0; nt < 2; ++nt) {
          f32x4 zr = {0.f, 0.f, 0.f, 0.f}, zi = {0.f, 0.f, 0.f, 0.f};
          zr = mfma16(Ar, bfrag[0][nt], zr);
          zr = mfma16(Ar, bfrag[1][nt], zr);
          zr = mfma16(Ai, bfrag[4][nt], zr);
          zr = mfma16(Ai, bfrag[5][nt], zr);
          zi = mfma16(Ar, bfrag[2][nt], zi);
          zi = mfma16(Ar, bfrag[3][nt], zi);
          zi = mfma16(Ai, bfrag[0][nt], zi);
          zi = mfma16(Ai, bfrag[1][nt], zi);
#pragma unroll
          for (int j = 0; j < 4; ++j) {
            int mrow = mt * 16 + ((lane >> 4) << 2) + j; // c*2+t
            int c = mrow >> 1, t = mrow & 1;
            int v = nt * 16 + (lane & 15);
            int pos2 = t * 32 + v;
            zbuf[SWZ(pos2, c)]      = f2bf(zr[j]);
            zbuf[SWZ(pos2, 64 + c)] = f2bf(zi[j]);
          }
        }
      }
    }
    __syncthreads();

    // phase B: y += Wd * zbuf
#pragma unroll
    for (int mtl = 0; mtl < 2; ++mtl) {
      int mt = wv * 2 + mtl;
      int arow = mt * 16 + (lane & 15);
#pragma unroll
      for (int ks = 0; ks < 4; ++ks) {
        short8 af = *(const short8*)&wdl[SWZ(arow, ks * 32 + ((lane >> 4) << 3))];
#pragma unroll
        for (int nt = 0; nt < 4; ++nt) {
          int brow = nt * 16 + (lane & 15);
          short8 bf = *(const short8*)&zbuf[SWZ(brow, ks * 32 + ((lane >> 4) << 3))];
          acc[mtl][nt] = mfma16(af, bf, acc[mtl][nt]);
        }
      }
    }
  }

  // epilogue: bias, write y, block-local BN partials (deterministic)
#pragma unroll
  for (int mtl = 0; mtl < 2; ++mtl) {
#pragma unroll
    for (int j = 0; j < 4; ++j) {
      int row = (wv * 2 + mtl) * 16 + ((lane >> 4) << 2) + j;
      float bias = bd[row] + bd[128 + row] + bd[256 + row];
      float s = 0.f, q = 0.f;
#pragma unroll
      for (int nt = 0; nt < 4; ++nt) {
        int pos2 = nt * 16 + (lane & 15);
        int t = pos2 >> 5, v = pos2 & 31;
        float val = acc[mtl][nt][j] + bias;
        if (v < VV) {
          int ri = row >> 6, o = row & 63;
          out[(size_t)ri * PLANE + (size_t)n * CTV + o * TV + (tc * 2 + t) * VV + v] = val;
          s += val; q += val * val;
        }
      }
#pragma unroll
      for (int d = 1; d < 16; d <<= 1) { s += __shfl_xor(s, d); q += __shfl_xor(q, d); }
      if ((lane & 15) == 0) { stats[row * 2] = s; stats[row * 2 + 1] = q; }
    }
  }
  __syncthreads();
  if (tid < 128) {
    size_t b = (size_t)(n * 128 + tc);
    bnpart[(b * 128 + tid) * 2]     = stats[tid * 2];
    bnpart[(b * 128 + tid) * 2 + 1] = stats[tid * 2 + 1];
  }
}

// ---------------------------------------------------------------------------
// K4: reduce bnpart -> per-channel coeff (mu_r, mu_i, scale, shift)
// ---------------------------------------------------------------------------
__global__ __launch_bounds__(256) void k4_stats(
    const float* __restrict__ bnpart, const float* __restrict__ bnw,
    const float* __restrict__ bnb, float* __restrict__ coeff)
{
  const int o = blockIdx.x, tid = threadIdx.x;
  float sr = 0.f, qr = 0.f, si = 0.f, qi = 0.f;
  for (int b = tid; b < 4096; b += 256) {
    const float* p = bnpart + ((size_t)b * 128 + o) * 2;
    sr += p[0]; qr += p[1];
    const float* p2 = bnpart + ((size_t)b * 128 + 64 + o) * 2;
    si += p2[0]; qi += p2[1];
  }
#pragma unroll
  for (int d = 1; d < 64; d <<= 1) {
    sr += __shfl_xor(sr, d); qr += __shfl_xor(qr, d);
    si += __shfl_xor(si, d); qi += __shfl_xor(qi, d);
  }
  __shared__ float red[4][4];
  int lane = tid & 63, wv = tid >> 6;
  if (lane == 0) { red[wv][0] = sr; red[wv][1] = qr; red[wv][2] = si; red[wv][3] = qi; }
  __syncthreads();
  if (tid == 0) {
    sr = red[0][0] + red[1][0] + red[2][0] + red[3][0];
    qr = red[0][1] + red[1][1] + red[2][1] + red[3][1];
    si = red[0][2] + red[1][2] + red[2][2] + red[3][2];
    qi = red[0][3] + red[1][3] + red[2][3] + red[3][3];
    const float invM = 1.f / (float)((size_t)NN * TTOT * VV);
    float mur = sr * invM, mui = si * invM;
    float var = (qr + qi) * invM - mur * mur - mui * mui;
    float inv = rsqrtf(var + 1e-5f);
    coeff[o * 4 + 0] = mur; coeff[o * 4 + 1] = mui;
    coeff[o * 4 + 2] = inv * bnw[o]; coeff[o * 4 + 3] = bnb[o];
  }
}

// ---------------------------------------------------------------------------
// K5: yn = (y - mu)*scale + shift + x  (in-place on d_out, vectorized)
// ---------------------------------------------------------------------------
__global__ __launch_bounds__(256) void k5_norm(
    const float* __restrict__ xr, const float* __restrict__ xi,
    const float* __restrict__ coeff, float* __restrict__ out)
{
  size_t idx0 = ((size_t)blockIdx.x * 256 + threadIdx.x) * 4;
  size_t stride = (size_t)gridDim.x * 256 * 4;
  for (size_t e = idx0; e < PLANE; e += stride) {
    int o = (int)((e / TV) & 63);
    float4 cf = *(const float4*)&coeff[o * 4];
    float4 yr = *(float4*)&out[e];
    float4 yi = *(float4*)&out[PLANE + e];
    float4 vr = *(const float4*)&xr[e];
    float4 vi = *(const float4*)&xi[e];
    yr.x = (yr.x - cf.x) * cf.z + cf.w + vr.x;
    yr.y = (yr.y - cf.x) * cf.z + cf.w + vr.y;
    yr.z = (yr.z - cf.x) * cf.z + cf.w + vr.z;
    yr.w = (yr.w - cf.x) * cf.z + cf.w + vr.w;
    yi.x = (yi.x - cf.y) * cf.z + vi.x;
    yi.y = (yi.y - cf.y) * cf.z + vi.y;
    yi.z = (yi.z - cf.y) * cf.z + vi.z;
    yi.w = (yi.w - cf.y) * cf.z + vi.w;
    *(float4*)&out[e] = yr;
    *(float4*)&out[PLANE + e] = yi;
  }
}

// ---------------------------------------------------------------------------
extern "C" void kernel_launch(void* const* d_in, const int* in_sizes, int n_in,
                              void* d_out, int out_size, void* d_ws, size_t ws_size,
                              hipStream_t stream) {
  const float* xr  = (const float*)d_in[0];
  const float* xi  = (const float*)d_in[1];
  const float* Aw  = (const float*)d_in[2];
  const float* PA  = (const float*)d_in[3];
  const float* Wa  = (const float*)d_in[4];
  const float* ba  = (const float*)d_in[5];
  const float* Wb  = (const float*)d_in[6];
  const float* bb  = (const float*)d_in[7];
  const float* Wd  = (const float*)d_in[8];
  const float* bd  = (const float*)d_in[9];
  const float* bnw = (const float*)d_in[10];
  const float* bnb = (const float*)d_in[11];
  float* out = (float*)d_out;
  float* ws = (float*)d_ws;

  float* Spart  = ws;                    // 3*32*64*625*2    = 7,680,000
  float* Sfin   = ws + 7680000;          // 3*32*625*2       =   120,000
  float* bnpart = ws + 7800000;          // 4096*128*2       = 1,048,576
  float* coeff  = ws + 8848576;          // 64*4             =       256

  k1_spart<<<dim3(64, NN), 256, 0, stream>>>(xr, xi, Wa, ba, Wb, bb, Spart);
  k2_softmax<<<dim3(NS, NN), 256, 0, stream>>>(Spart, Aw, PA, Sfin);
  k3_y<<<dim3(128, NN), 256, 0, stream>>>(xr, xi, Sfin, Wd, bd, out, bnpart);
  k4_stats<<<64, 256, 0, stream>>>(bnpart, bnw, bnb, coeff);
  k5_norm<<<6400, 256, 0, stream>>>(xr, xi, coeff, out);
}

// Round 2
// 488.562 us; speedup vs baseline: 3.6290x; 3.6290x over previous
//
#include <hip/hip_runtime.h>
#include <hip/hip_bf16.h>
#include <stdint.h>

#define NN 32
#define CC 64
#define TTOT 256
#define VV 25
#define NS 3
constexpr int TV  = TTOT * VV;            // 6400
constexpr int CTV = CC * TV;              // 409600
constexpr size_t PLANE = (size_t)NN * CTV; // 13107200

typedef unsigned short ushort_t;
using short8 = __attribute__((ext_vector_type(8))) short;
using f32x4  = __attribute__((ext_vector_type(4))) float;

static __device__ __forceinline__ ushort_t f2bf(float f) {
  union { float f; uint32_t u; } v; v.f = f;
  return (ushort_t)((v.u + 0x7FFFu + ((v.u >> 16) & 1u)) >> 16);
}
static __device__ __forceinline__ float bf2f(ushort_t h) {
  union { uint32_t u; float f; } v; v.u = ((uint32_t)h) << 16;
  return v.f;
}
// element offset into a [row][128] bf16 tile, XOR-swizzled (byte ^= (row&7)<<4)
static __device__ __forceinline__ int SWZ(int row, int k) {
  return ((row << 7) + k) ^ ((row & 7) << 3);
}
static __device__ __forceinline__ f32x4 mfma16(short8 a, short8 b, f32x4 c) {
  return __builtin_amdgcn_mfma_f32_16x16x32_bf16(a, b, c, 0, 0, 0);
}

// ---------------------------------------------------------------------------
// K1: per (n, tc) with 4 t's: conv (MFMA) -> Ga/Gb transposed in LDS ->
//     Gram via MFMA (25x25, K=64). Spart[3][32][64][25][25][2]
// ---------------------------------------------------------------------------
__global__ __launch_bounds__(256) void k1_spart(
    const float* __restrict__ xr, const float* __restrict__ xi,
    const float* __restrict__ Wa, const float* __restrict__ ba,
    const float* __restrict__ Wb, const float* __restrict__ bb,
    float* __restrict__ Spart)
{
  const int tc = blockIdx.x, n = blockIdx.y;
  const int tid = threadIdx.x, lane = tid & 63, wv = tid >> 6;
  __shared__ alignas(16) ushort_t zc[128 * 128]; // [pos2=t*32+v][c] swizzled
  __shared__ alignas(16) ushort_t wl[64 * 128];  // [row][c] swizzled
  __shared__ alignas(16) ushort_t Ga[32 * 128];  // [u][k: ar 0-63, ai 64-127] swz
  __shared__ alignas(16) ushort_t Gb[32 * 128];  // [v][k: br 0-63, bi 64-127] swz

  // stage zc: float4 loads (100 contiguous floats per c = 25 float4)
  for (int e4 = tid; e4 < 128 * 25; e4 += 256) {
    int c = e4 / 25, q = e4 % 25;
    const float* src = (c < 64) ? xr : xi;
    float4 w = *(const float4*)&src[(size_t)n * CTV + (c & 63) * TV + tc * 100 + q * 4];
#pragma unroll
    for (int jj = 0; jj < 4; ++jj) {
      int g = q * 4 + jj, t = g / 25, v = g - t * 25;
      zc[SWZ(t * 32 + v, c)] = f2bf(((const float*)&w)[jj]);
    }
  }
  // zero-pad v=25..31
  for (int e = tid; e < 28 * 128; e += 256) {
    int r7 = e >> 7, c = e & 127;
    int t = r7 / 7, vv = 25 + r7 % 7;
    zc[SWZ(t * 32 + vv, c)] = 0;
  }

  const int mu = wv >> 1, nv = wv & 1;

  for (int i = 0; i < NS; ++i) {
    __syncthreads(); // zc ready (i==0); WAR on wl/Ga/Gb vs previous iter

    // stage weights (float4): rows 0..31 = Wa[i], 32..63 = Wb[i]
    for (int e4 = tid; e4 < 64 * 32; e4 += 256) {
      int r = e4 >> 5, c4 = (e4 & 31) * 4;
      const float* w = (r < 32) ? (Wa + (size_t)(i * 32 + r) * 128)
                                : (Wb + (size_t)(i * 32 + (r - 32)) * 128);
      float4 wf = *(const float4*)&w[c4];
#pragma unroll
      for (int jj = 0; jj < 4; ++jj) wl[SWZ(r, c4 + jj)] = f2bf(((const float*)&wf)[jj]);
    }
    __syncthreads();

    // conv: wave wv owns output rows [wv*16, wv*16+16) -> all one component
    {
      const int mt = wv;
      const int arow = mt * 16 + (lane & 15);
      short8 afr[4];
#pragma unroll
      for (int ks = 0; ks < 4; ++ks)
        afr[ks] = *(const short8*)&wl[SWZ(arow, ks * 32 + ((lane >> 4) << 3))];
      float bias[4];
#pragma unroll
      for (int j = 0; j < 4; ++j) {
        int row = mt * 16 + ((lane >> 4) << 2) + j;
        bias[j] = (row < 32) ? ba[i * 32 + row] : bb[i * 32 + (row - 32)];
      }
      const int comp = mt;               // 0=ar 1=ai 2=br 3=bi
      ushort_t* gbuf = (comp < 2) ? Ga : Gb;
      const int half = (comp & 1) * 64;
      for (int nt = 0; nt < 8; ++nt) {
        f32x4 acc = {0.f, 0.f, 0.f, 0.f};
        const int brow = nt * 16 + (lane & 15);
#pragma unroll
        for (int ks = 0; ks < 4; ++ks) {
          short8 bfr = *(const short8*)&zc[SWZ(brow, ks * 32 + ((lane >> 4) << 3))];
          acc = mfma16(afr[ks], bfr, acc);
        }
#pragma unroll
        for (int j = 0; j < 4; ++j) {
          int it = ((lane >> 4) << 2) + j;       // row&15
          int pos2 = nt * 16 + (lane & 15);
          int t = pos2 >> 5, v = pos2 & 31;
          gbuf[SWZ(v, half + it * 4 + t)] = f2bf(acc[j] + bias[j]);
        }
      }
    }
    __syncthreads();

    // Gram via MFMA: wave (mu,nv) computes S[mu*16..+16)[nv*16..+16)
    {
      const int urow = mu * 16 + (lane & 15);
      const int vrow = nv * 16 + (lane & 15);
      f32x4 Prr = {0.f,0.f,0.f,0.f}, Pii = {0.f,0.f,0.f,0.f};
      f32x4 Pri = {0.f,0.f,0.f,0.f}, Pir = {0.f,0.f,0.f,0.f};
#pragma unroll
      for (int ks = 0; ks < 2; ++ks) {
        int ko = ks * 32 + ((lane >> 4) << 3);
        short8 arF = *(const short8*)&Ga[SWZ(urow, ko)];
        short8 aiF = *(const short8*)&Ga[SWZ(urow, 64 + ko)];
        short8 brF = *(const short8*)&Gb[SWZ(vrow, ko)];
        short8 biF = *(const short8*)&Gb[SWZ(vrow, 64 + ko)];
        Prr = mfma16(arF, brF, Prr);
        Pii = mfma16(aiF, biF, Pii);
        Pri = mfma16(arF, biF, Pri);
        Pir = mfma16(aiF, brF, Pir);
      }
#pragma unroll
      for (int j = 0; j < 4; ++j) {
        int u = mu * 16 + ((lane >> 4) << 2) + j;
        int v = nv * 16 + (lane & 15);
        if (u < VV && v < VV) {
          size_t idx = ((((size_t)i * NN + n) * 64 + tc) * 625 + u * 25 + v) * 2;
          Spart[idx]     = Prr[j] - Pii[j];
          Spart[idx + 1] = Pri[j] + Pir[j];
        }
      }
    }
  }
}

// ---------------------------------------------------------------------------
// K2: reduce Spart over tc, /4096, complex softmax over u, + (A+PA)
// ---------------------------------------------------------------------------
__global__ __launch_bounds__(256) void k2_softmax(
    const float* __restrict__ Spart, const float* __restrict__ Aw,
    const float* __restrict__ PA, float* __restrict__ Sfin)
{
  const int i = blockIdx.x, n = blockIdx.y, tid = threadIdx.x;
  __shared__ float ez[625 * 2];
  __shared__ float den[25 * 2];
  for (int e = tid; e < 625; e += 256) {
    float sr = 0.f, si = 0.f;
    const float* p = Spart + (((size_t)i * NN + n) * 64 * 625 + e) * 2;
    for (int tcb = 0; tcb < 64; ++tcb) { sr += p[0]; si += p[1]; p += 625 * 2; }
    sr *= (1.f / 4096.f); si *= (1.f / 4096.f);
    float m = expf(sr);
    ez[e * 2] = m * cosf(si);
    ez[e * 2 + 1] = m * sinf(si);
  }
  __syncthreads();
  if (tid < 25) {
    float dr = 0.f, di = 0.f;
    for (int u = 0; u < 25; ++u) { dr += ez[(u * 25 + tid) * 2]; di += ez[(u * 25 + tid) * 2 + 1]; }
    float inv = 1.f / (dr * dr + di * di);
    den[tid * 2] = dr * inv; den[tid * 2 + 1] = -di * inv; // conj(d)/|d|^2
  }
  __syncthreads();
  for (int e = tid; e < 625; e += 256) {
    int v = e % 25;
    float er = ez[e * 2], ei = ez[e * 2 + 1];
    float dr = den[v * 2], di = den[v * 2 + 1];
    float outr = er * dr - ei * di + Aw[i * 625 + e] + PA[i * 625 + e];
    float outi = er * di + ei * dr;
    size_t o = (((size_t)i * NN + n) * 625 + e) * 2;
    Sfin[o] = outr; Sfin[o + 1] = outi;
  }
}

// ---------------------------------------------------------------------------
// K3: per (n, tc) with 2 t's: z = X2*S (MFMA, S hi/lo split), Wd conv (MFMA),
//     accumulate over i, write y into d_out, block-local BN partials.
// ---------------------------------------------------------------------------
__global__ __launch_bounds__(256) void k3_y(
    const float* __restrict__ xr, const float* __restrict__ xi,
    const float* __restrict__ Sfin, const float* __restrict__ Wd,
    const float* __restrict__ bd, float* __restrict__ out,
    float* __restrict__ bnpart)
{
  const int tc = blockIdx.x, n = blockIdx.y;
  const int tid = threadIdx.x, lane = tid & 63, wv = tid >> 6;
  __shared__ alignas(16) ushort_t zcA[16 * 64 * 8];   // prefrag [mt][lane][8]
  __shared__ alignas(16) ushort_t sfr[6 * 2 * 64 * 8]; // [combo][nt][lane][8]
  __shared__ alignas(16) ushort_t zbuf[64 * 128];      // [pos2][k] swizzled
  __shared__ alignas(16) ushort_t wdl[128 * 128];      // [row][k] swizzled
  __shared__ float stats[128 * 2];

  // stage zcA: rows m = (imag?128:0) + c*2 + t, k = u (u>=25 zero)
  for (int e = tid; e < 8192; e += 256) {
    int u = e & 31, t = (e >> 5) & 1, cj = e >> 6;
    float val = 0.f;
    if (u < VV) {
      const float* src = (cj < 64) ? xr : xi;
      val = src[(size_t)n * CTV + (cj & 63) * TV + (tc * 2 + t) * VV + u];
    }
    int mrow = ((cj < 64) ? 0 : 128) + ((cj & 63) << 1) + t;
    int off = ((mrow >> 4) * 64 + (mrow & 15) + ((u >> 3) << 4)) * 8 + (u & 7);
    zcA[off] = f2bf(val);
  }

  f32x4 acc[2][4];
#pragma unroll
  for (int a = 0; a < 2; ++a)
#pragma unroll
    for (int b = 0; b < 4; ++b) acc[a][b] = {0.f, 0.f, 0.f, 0.f};

  for (int i = 0; i < NS; ++i) {
    __syncthreads(); // zcA ready / zbuf,sfr,wdl WAR vs previous iteration

    // stage S fragments: combos {Srh,Srl,Sih,Sil,-Sih,-Sil}
    for (int e = tid; e < 6 * 2 * 64; e += 256) {
      int l = e & 63, nt = (e >> 6) & 1, m = e >> 7;
      int u0 = (l >> 4) << 3, v = nt * 16 + (l & 15);
      short8 pk;
#pragma unroll
      for (int j = 0; j < 8; ++j) {
        int u = u0 + j;
        float val = 0.f;
        if (u < VV && v < VV) {
          const float* sp = Sfin + (((size_t)i * NN + n) * 625 + u * 25 + v) * 2;
          float base = (m < 2) ? sp[0] : (m < 4) ? sp[1] : -sp[1];
          if (m & 1) { float hi = bf2f(f2bf(base)); val = base - hi; }
          else val = base;
        }
        pk[j] = (short)f2bf(val);
      }
      *(short8*)&sfr[e * 8] = pk;
    }
    // stage Wd[i] (direct copy of [128][128])
    for (int e = tid; e < 16384; e += 256) {
      int k = e & 127, r = e >> 7;
      wdl[SWZ(r, k)] = f2bf(Wd[(size_t)i * 16384 + e]);
    }
    __syncthreads();

    // phase A: z = X2 * S  (complex via real MFMAs, hi+lo S)
    {
      short8 bfrag[6][2];
#pragma unroll
      for (int m = 0; m < 6; ++m)
#pragma unroll
        for (int nt = 0; nt < 2; ++nt)
          bfrag[m][nt] = *(const short8*)&sfr[((m * 2 + nt) * 64 + lane) * 8];
#pragma unroll
      for (int mtl = 0; mtl < 2; ++mtl) {
        int mt = wv * 2 + mtl;
        short8 Ar = *(const short8*)&zcA[(mt * 64 + lane) * 8];
        short8 Ai = *(const short8*)&zcA[((mt + 8) * 64 + lane) * 8];
#pragma unroll
        for (int nt = 0; nt < 2; ++nt) {
          f32x4 zr = {0.f, 0.f, 0.f, 0.f}, zi = {0.f, 0.f, 0.f, 0.f};
          zr = mfma16(Ar, bfrag[0][nt], zr);
          zr = mfma16(Ar, bfrag[1][nt], zr);
          zr = mfma16(Ai, bfrag[4][nt], zr);
          zr = mfma16(Ai, bfrag[5][nt], zr);
          zi = mfma16(Ar, bfrag[2][nt], zi);
          zi = mfma16(Ar, bfrag[3][nt], zi);
          zi = mfma16(Ai, bfrag[0][nt], zi);
          zi = mfma16(Ai, bfrag[1][nt], zi);
#pragma unroll
          for (int j = 0; j < 4; ++j) {
            int mrow = mt * 16 + ((lane >> 4) << 2) + j; // c*2+t
            int c = mrow >> 1, t = mrow & 1;
            int v = nt * 16 + (lane & 15);
            int pos2 = t * 32 + v;
            zbuf[SWZ(pos2, c)]      = f2bf(zr[j]);
            zbuf[SWZ(pos2, 64 + c)] = f2bf(zi[j]);
          }
        }
      }
    }
    __syncthreads();

    // phase B: y += Wd * zbuf
#pragma unroll
    for (int mtl = 0; mtl < 2; ++mtl) {
      int mt = wv * 2 + mtl;
      int arow = mt * 16 + (lane & 15);
#pragma unroll
      for (int ks = 0; ks < 4; ++ks) {
        short8 af = *(const short8*)&wdl[SWZ(arow, ks * 32 + ((lane >> 4) << 3))];
#pragma unroll
        for (int nt = 0; nt < 4; ++nt) {
          int brow = nt * 16 + (lane & 15);
          short8 bf = *(const short8*)&zbuf[SWZ(brow, ks * 32 + ((lane >> 4) << 3))];
          acc[mtl][nt] = mfma16(af, bf, acc[mtl][nt]);
        }
      }
    }
  }

  // epilogue: bias, write y, block-local BN partials (deterministic)
#pragma unroll
  for (int mtl = 0; mtl < 2; ++mtl) {
#pragma unroll
    for (int j = 0; j < 4; ++j) {
      int row = (wv * 2 + mtl) * 16 + ((lane >> 4) << 2) + j;
      float bias = bd[row] + bd[128 + row] + bd[256 + row];
      float s = 0.f, q = 0.f;
#pragma unroll
      for (int nt = 0; nt < 4; ++nt) {
        int pos2 = nt * 16 + (lane & 15);
        int t = pos2 >> 5, v = pos2 & 31;
        float val = acc[mtl][nt][j] + bias;
        if (v < VV) {
          int ri = row >> 6, o = row & 63;
          out[(size_t)ri * PLANE + (size_t)n * CTV + o * TV + (tc * 2 + t) * VV + v] = val;
          s += val; q += val * val;
        }
      }
#pragma unroll
      for (int d = 1; d < 16; d <<= 1) { s += __shfl_xor(s, d); q += __shfl_xor(q, d); }
      if ((lane & 15) == 0) { stats[row * 2] = s; stats[row * 2 + 1] = q; }
    }
  }
  __syncthreads();
  if (tid < 128) {
    size_t b = (size_t)(n * 128 + tc);
    bnpart[(b * 128 + tid) * 2]     = stats[tid * 2];
    bnpart[(b * 128 + tid) * 2 + 1] = stats[tid * 2 + 1];
  }
}

// ---------------------------------------------------------------------------
// K4: reduce bnpart -> per-channel coeff (mu_r, mu_i, scale, shift)
// ---------------------------------------------------------------------------
__global__ __launch_bounds__(256) void k4_stats(
    const float* __restrict__ bnpart, const float* __restrict__ bnw,
    const float* __restrict__ bnb, float* __restrict__ coeff)
{
  const int o = blockIdx.x, tid = threadIdx.x;
  float sr = 0.f, qr = 0.f, si = 0.f, qi = 0.f;
  for (int b = tid; b < 4096; b += 256) {
    const float* p = bnpart + ((size_t)b * 128 + o) * 2;
    sr += p[0]; qr += p[1];
    const float* p2 = bnpart + ((size_t)b * 128 + 64 + o) * 2;
    si += p2[0]; qi += p2[1];
  }
#pragma unroll
  for (int d = 1; d < 64; d <<= 1) {
    sr += __shfl_xor(sr, d); qr += __shfl_xor(qr, d);
    si += __shfl_xor(si, d); qi += __shfl_xor(qi, d);
  }
  __shared__ float red[4][4];
  int lane = tid & 63, wv = tid >> 6;
  if (lane == 0) { red[wv][0] = sr; red[wv][1] = qr; red[wv][2] = si; red[wv][3] = qi; }
  __syncthreads();
  if (tid == 0) {
    sr = red[0][0] + red[1][0] + red[2][0] + red[3][0];
    qr = red[0][1] + red[1][1] + red[2][1] + red[3][1];
    si = red[0][2] + red[1][2] + red[2][2] + red[3][2];
    qi = red[0][3] + red[1][3] + red[2][3] + red[3][3];
    const float invM = 1.f / (float)((size_t)NN * TTOT * VV);
    float mur = sr * invM, mui = si * invM;
    float var = (qr + qi) * invM - mur * mur - mui * mui;
    float inv = rsqrtf(var + 1e-5f);
    coeff[o * 4 + 0] = mur; coeff[o * 4 + 1] = mui;
    coeff[o * 4 + 2] = inv * bnw[o]; coeff[o * 4 + 3] = bnb[o];
  }
}

// ---------------------------------------------------------------------------
// K5: yn = (y - mu)*scale + shift + x  (in-place on d_out, vectorized)
// ---------------------------------------------------------------------------
__global__ __launch_bounds__(256) void k5_norm(
    const float* __restrict__ xr, const float* __restrict__ xi,
    const float* __restrict__ coeff, float* __restrict__ out)
{
  size_t idx0 = ((size_t)blockIdx.x * 256 + threadIdx.x) * 4;
  size_t stride = (size_t)gridDim.x * 256 * 4;
  for (size_t e = idx0; e < PLANE; e += stride) {
    int o = (int)((e / TV) & 63);
    float4 cf = *(const float4*)&coeff[o * 4];
    float4 yr = *(float4*)&out[e];
    float4 yi = *(float4*)&out[PLANE + e];
    float4 vr = *(const float4*)&xr[e];
    float4 vi = *(const float4*)&xi[e];
    yr.x = (yr.x - cf.x) * cf.z + cf.w + vr.x;
    yr.y = (yr.y - cf.x) * cf.z + cf.w + vr.y;
    yr.z = (yr.z - cf.x) * cf.z + cf.w + vr.z;
    yr.w = (yr.w - cf.x) * cf.z + cf.w + vr.w;
    yi.x = (yi.x - cf.y) * cf.z + vi.x;
    yi.y = (yi.y - cf.y) * cf.z + vi.y;
    yi.z = (yi.z - cf.y) * cf.z + vi.z;
    yi.w = (yi.w - cf.y) * cf.z + vi.w;
    *(float4*)&out[e] = yr;
    *(float4*)&out[PLANE + e] = yi;
  }
}

// ---------------------------------------------------------------------------
extern "C" void kernel_launch(void* const* d_in, const int* in_sizes, int n_in,
                              void* d_out, int out_size, void* d_ws, size_t ws_size,
                              hipStream_t stream) {
  const float* xr  = (const float*)d_in[0];
  const float* xi  = (const float*)d_in[1];
  const float* Aw  = (const float*)d_in[2];
  const float* PA  = (const float*)d_in[3];
  const float* Wa  = (const float*)d_in[4];
  const float* ba  = (const float*)d_in[5];
  const float* Wb  = (const float*)d_in[6];
  const float* bb  = (const float*)d_in[7];
  const float* Wd  = (const float*)d_in[8];
  const float* bd  = (const float*)d_in[9];
  const float* bnw = (const float*)d_in[10];
  const float* bnb = (const float*)d_in[11];
  float* out = (float*)d_out;
  float* ws = (float*)d_ws;

  float* Spart  = ws;                    // 3*32*64*625*2    = 7,680,000
  float* Sfin   = ws + 7680000;          // 3*32*625*2       =   120,000
  float* bnpart = ws + 7800000;          // 4096*128*2       = 1,048,576
  float* coeff  = ws + 8848576;          // 64*4             =       256

  k1_spart<<<dim3(64, NN), 256, 0, stream>>>(xr, xi, Wa, ba, Wb, bb, Spart);
  k2_softmax<<<dim3(NS, NN), 256, 0, stream>>>(Spart, Aw, PA, Sfin);
  k3_y<<<dim3(128, NN), 256, 0, stream>>>(xr, xi, Sfin, Wd, bd, out, bnpart);
  k4_stats<<<64, 256, 0, stream>>>(bnpart, bnw, bnb, coeff);
  k5_norm<<<6400, 256, 0, stream>>>(xr, xi, coeff, out);
}

// Round 3
// 297.562 us; speedup vs baseline: 5.9584x; 1.6419x over previous
//
#include <hip/hip_runtime.h>
#include <hip/hip_bf16.h>
#include <stdint.h>

#define NN 32
#define CC 64
#define TTOT 256
#define VV 25
#define NS 3
constexpr int TV  = TTOT * VV;            // 6400
constexpr int CTV = CC * TV;              // 409600
constexpr size_t PLANE = (size_t)NN * CTV; // 13107200

typedef unsigned short ushort_t;
using short8 = __attribute__((ext_vector_type(8))) short;
using f32x4  = __attribute__((ext_vector_type(4))) float;

static __device__ __forceinline__ ushort_t f2bf(float f) {
  union { float f; uint32_t u; } v; v.f = f;
  return (ushort_t)((v.u + 0x7FFFu + ((v.u >> 16) & 1u)) >> 16);
}
static __device__ __forceinline__ float bf2f(ushort_t h) {
  union { uint32_t u; float f; } v; v.u = ((uint32_t)h) << 16;
  return v.f;
}
// element offset into a [row][128] bf16 tile, XOR-swizzled (byte ^= (row&7)<<4)
static __device__ __forceinline__ int SWZ(int row, int k) {
  return ((row << 7) + k) ^ ((row & 7) << 3);
}
static __device__ __forceinline__ f32x4 mfma16(short8 a, short8 b, f32x4 c) {
  return __builtin_amdgcn_mfma_f32_16x16x32_bf16(a, b, c, 0, 0, 0);
}

// ---------------------------------------------------------------------------
// K0: pre-fragment Wd into bf16, column-permuted to interleaved k'=2c+comp.
// Layout: wfrag[i][mt(8)][ks(4)][lane(64)][j(8)] so k3's per-lane 16B load
// (((i*8+mt)*4+ks)*64+lane)*8 is fully coalesced.
// ---------------------------------------------------------------------------
__global__ __launch_bounds__(256) void k0_wfrag(
    const float* __restrict__ Wd, ushort_t* __restrict__ wfrag)
{
  const int i = blockIdx.x;
  for (int e = threadIdx.x; e < 16384; e += 256) {
    int mt = e >> 11;
    int ks = (e >> 9) & 3;
    int l  = (e >> 3) & 63;
    int j  = e & 7;
    int r  = mt * 16 + (l & 15);
    int kp = ks * 32 + ((l >> 4) << 3) + j;   // interleaved channel index
    int c = kp >> 1, comp = kp & 1;
    wfrag[(size_t)i * 16384 + e] = f2bf(Wd[(size_t)i * 16384 + r * 128 + comp * 64 + c]);
  }
}

// ---------------------------------------------------------------------------
// K1: per (n, tc) with 4 t's: conv (MFMA) -> Ga/Gb transposed in LDS ->
//     Gram via MFMA (25x25, K=64). Spart[3][32][64][25][25][2]
// ---------------------------------------------------------------------------
__global__ __launch_bounds__(256) void k1_spart(
    const float* __restrict__ xr, const float* __restrict__ xi,
    const float* __restrict__ Wa, const float* __restrict__ ba,
    const float* __restrict__ Wb, const float* __restrict__ bb,
    float* __restrict__ Spart)
{
  const int tc = blockIdx.x, n = blockIdx.y;
  const int tid = threadIdx.x, lane = tid & 63, wv = tid >> 6;
  __shared__ alignas(16) ushort_t zc[128 * 128]; // [pos2=t*32+v][c] swizzled
  __shared__ alignas(16) ushort_t wl[64 * 128];  // [row][c] swizzled
  __shared__ alignas(16) ushort_t Ga[32 * 128];  // [u][k: ar 0-63, ai 64-127] swz
  __shared__ alignas(16) ushort_t Gb[32 * 128];  // [v][k: br 0-63, bi 64-127] swz

  // stage zc: float4 loads (100 contiguous floats per c = 25 float4)
  for (int e4 = tid; e4 < 128 * 25; e4 += 256) {
    int c = e4 / 25, q = e4 % 25;
    const float* src = (c < 64) ? xr : xi;
    float4 w = *(const float4*)&src[(size_t)n * CTV + (c & 63) * TV + tc * 100 + q * 4];
#pragma unroll
    for (int jj = 0; jj < 4; ++jj) {
      int g = q * 4 + jj, t = g / 25, v = g - t * 25;
      zc[SWZ(t * 32 + v, c)] = f2bf(((const float*)&w)[jj]);
    }
  }
  // zero-pad v=25..31
  for (int e = tid; e < 28 * 128; e += 256) {
    int r7 = e >> 7, c = e & 127;
    int t = r7 / 7, vv = 25 + r7 % 7;
    zc[SWZ(t * 32 + vv, c)] = 0;
  }

  const int mu = wv >> 1, nv = wv & 1;

  for (int i = 0; i < NS; ++i) {
    __syncthreads(); // zc ready (i==0); WAR on wl/Ga/Gb vs previous iter

    // stage weights (float4): rows 0..31 = Wa[i], 32..63 = Wb[i]
    for (int e4 = tid; e4 < 64 * 32; e4 += 256) {
      int r = e4 >> 5, c4 = (e4 & 31) * 4;
      const float* w = (r < 32) ? (Wa + (size_t)(i * 32 + r) * 128)
                                : (Wb + (size_t)(i * 32 + (r - 32)) * 128);
      float4 wf = *(const float4*)&w[c4];
#pragma unroll
      for (int jj = 0; jj < 4; ++jj) wl[SWZ(r, c4 + jj)] = f2bf(((const float*)&wf)[jj]);
    }
    __syncthreads();

    // conv: wave wv owns output rows [wv*16, wv*16+16) -> all one component
    {
      const int mt = wv;
      const int arow = mt * 16 + (lane & 15);
      short8 afr[4];
#pragma unroll
      for (int ks = 0; ks < 4; ++ks)
        afr[ks] = *(const short8*)&wl[SWZ(arow, ks * 32 + ((lane >> 4) << 3))];
      float bias[4];
#pragma unroll
      for (int j = 0; j < 4; ++j) {
        int row = mt * 16 + ((lane >> 4) << 2) + j;
        bias[j] = (row < 32) ? ba[i * 32 + row] : bb[i * 32 + (row - 32)];
      }
      const int comp = mt;               // 0=ar 1=ai 2=br 3=bi
      ushort_t* gbuf = (comp < 2) ? Ga : Gb;
      const int half = (comp & 1) * 64;
      for (int nt = 0; nt < 8; ++nt) {
        f32x4 acc = {0.f, 0.f, 0.f, 0.f};
        const int brow = nt * 16 + (lane & 15);
#pragma unroll
        for (int ks = 0; ks < 4; ++ks) {
          short8 bfr = *(const short8*)&zc[SWZ(brow, ks * 32 + ((lane >> 4) << 3))];
          acc = mfma16(afr[ks], bfr, acc);
        }
#pragma unroll
        for (int j = 0; j < 4; ++j) {
          int it = ((lane >> 4) << 2) + j;       // row&15
          int pos2 = nt * 16 + (lane & 15);
          int t = pos2 >> 5, v = pos2 & 31;
          gbuf[SWZ(v, half + it * 4 + t)] = f2bf(acc[j] + bias[j]);
        }
      }
    }
    __syncthreads();

    // Gram via MFMA: wave (mu,nv) computes S[mu*16..+16)[nv*16..+16)
    {
      const int urow = mu * 16 + (lane & 15);
      const int vrow = nv * 16 + (lane & 15);
      f32x4 Prr = {0.f,0.f,0.f,0.f}, Pii = {0.f,0.f,0.f,0.f};
      f32x4 Pri = {0.f,0.f,0.f,0.f}, Pir = {0.f,0.f,0.f,0.f};
#pragma unroll
      for (int ks = 0; ks < 2; ++ks) {
        int ko = ks * 32 + ((lane >> 4) << 3);
        short8 arF = *(const short8*)&Ga[SWZ(urow, ko)];
        short8 aiF = *(const short8*)&Ga[SWZ(urow, 64 + ko)];
        short8 brF = *(const short8*)&Gb[SWZ(vrow, ko)];
        short8 biF = *(const short8*)&Gb[SWZ(vrow, 64 + ko)];
        Prr = mfma16(arF, brF, Prr);
        Pii = mfma16(aiF, biF, Pii);
        Pri = mfma16(arF, biF, Pri);
        Pir = mfma16(aiF, brF, Pir);
      }
#pragma unroll
      for (int j = 0; j < 4; ++j) {
        int u = mu * 16 + ((lane >> 4) << 2) + j;
        int v = nv * 16 + (lane & 15);
        if (u < VV && v < VV) {
          size_t idx = ((((size_t)i * NN + n) * 64 + tc) * 625 + u * 25 + v) * 2;
          Spart[idx]     = Prr[j] - Pii[j];
          Spart[idx + 1] = Pri[j] + Pir[j];
        }
      }
    }
  }
}

// ---------------------------------------------------------------------------
// K2: reduce Spart over tc, /4096, complex softmax over u, + (A+PA),
//     then emit packed bf16 hi/lo S-fragments in per-lane MFMA order.
// sfrag[i][n][m(6)][nt(2)][lane(64)][j(8)]  (m: Srh,Srl,Sih,Sil,-Sih,-Sil)
// ---------------------------------------------------------------------------
__global__ __launch_bounds__(256) void k2_softmax(
    const float* __restrict__ Spart, const float* __restrict__ Aw,
    const float* __restrict__ PA, ushort_t* __restrict__ sfrag)
{
  const int i = blockIdx.x, n = blockIdx.y, tid = threadIdx.x;
  __shared__ float ez[625 * 2];
  __shared__ float den[25 * 2];
  for (int e = tid; e < 625; e += 256) {
    float sr = 0.f, si = 0.f;
    const float* p = Spart + (((size_t)i * NN + n) * 64 * 625 + e) * 2;
    for (int tcb = 0; tcb < 64; ++tcb) { sr += p[0]; si += p[1]; p += 625 * 2; }
    sr *= (1.f / 4096.f); si *= (1.f / 4096.f);
    float m = expf(sr);
    ez[e * 2] = m * cosf(si);
    ez[e * 2 + 1] = m * sinf(si);
  }
  __syncthreads();
  if (tid < 25) {
    float dr = 0.f, di = 0.f;
    for (int u = 0; u < 25; ++u) { dr += ez[(u * 25 + tid) * 2]; di += ez[(u * 25 + tid) * 2 + 1]; }
    float inv = 1.f / (dr * dr + di * di);
    den[tid * 2] = dr * inv; den[tid * 2 + 1] = -di * inv; // conj(d)/|d|^2
  }
  __syncthreads();
  for (int e = tid; e < 625; e += 256) {
    int v = e % 25;
    float er = ez[e * 2], ei = ez[e * 2 + 1];
    float dr = den[v * 2], di = den[v * 2 + 1];
    float outr = er * dr - ei * di + Aw[i * 625 + e] + PA[i * 625 + e];
    float outi = er * di + ei * dr;
    ez[e * 2] = outr; ez[e * 2 + 1] = outi;   // finalize in place
  }
  __syncthreads();
  // pack fragments
  for (int e = tid; e < 768; e += 256) {
    int l = e & 63, nt = (e >> 6) & 1, m = e >> 7;
    int u0 = (l >> 4) << 3, v = nt * 16 + (l & 15);
    short8 pk;
#pragma unroll
    for (int j = 0; j < 8; ++j) {
      int u = u0 + j;
      float val = 0.f;
      if (u < VV && v < VV) {
        float sr_ = ez[(u * 25 + v) * 2], si_ = ez[(u * 25 + v) * 2 + 1];
        float base = (m < 2) ? sr_ : (m < 4) ? si_ : -si_;
        if (m & 1) { float hi = bf2f(f2bf(base)); val = base - hi; }
        else val = base;
      }
      pk[j] = (short)f2bf(val);
    }
    *(short8*)&sfrag[((size_t)(i * NN + n) * 768 + e) * 8] = pk;
  }
}

// ---------------------------------------------------------------------------
// K3: per (n, tc) with 2 t's. All operands except zbuf live in registers:
//   x A-frags: direct global loads; S b-frags + Wd a-frags: precomputed
//   fragment buffers (L2-hot coalesced 16B loads). LDS = zbuf only (16KB).
// ---------------------------------------------------------------------------
__global__ __launch_bounds__(256) void k3_y(
    const float* __restrict__ xr, const float* __restrict__ xi,
    const ushort_t* __restrict__ sfrag, const ushort_t* __restrict__ wfrag,
    const float* __restrict__ bd, float* __restrict__ out,
    float* __restrict__ bnpart)
{
  const int tc = blockIdx.x, n = blockIdx.y;
  const int tid = threadIdx.x, lane = tid & 63, wv = tid >> 6;
  __shared__ alignas(16) ushort_t zbuf[64 * 128]; // [pos2][k'=2c+comp] swizzled
  __shared__ float stats[128 * 2];

  // x A-fragments, straight into registers (rows are 25-stride -> scalar loads)
  short8 xf[2][2]; // [mtl][comp]
  {
    const int u0 = (lane >> 4) << 3;
#pragma unroll
    for (int mtl = 0; mtl < 2; ++mtl) {
      int mrow = (wv * 2 + mtl) * 16 + (lane & 15);
      int c = mrow >> 1, t = mrow & 1;
#pragma unroll
      for (int comp = 0; comp < 2; ++comp) {
        const float* p = (comp ? xi : xr) + (size_t)n * CTV + c * TV + (tc * 2 + t) * VV;
        short8 f;
#pragma unroll
        for (int j = 0; j < 8; ++j) {
          int u = u0 + j;
          f[j] = (u < VV) ? (short)f2bf(p[u]) : (short)0;
        }
        xf[mtl][comp] = f;
      }
    }
  }

  f32x4 acc[2][4];
#pragma unroll
  for (int a = 0; a < 2; ++a)
#pragma unroll
    for (int b = 0; b < 4; ++b) acc[a][b] = {0.f, 0.f, 0.f, 0.f};

  for (int i = 0; i < NS; ++i) {
    // S fragments for this (i, n): 12 coalesced 16B loads (L2-hot)
    const ushort_t* sb = sfrag + (size_t)(i * NN + n) * 6144;
    short8 bfrag[6][2];
#pragma unroll
    for (int m = 0; m < 6; ++m)
#pragma unroll
      for (int nt = 0; nt < 2; ++nt)
        bfrag[m][nt] = *(const short8*)&sb[((m * 2 + nt) * 64 + lane) * 8];

    // phase A: z = X2 * S  (complex via real MFMAs, hi+lo S), packed u32 writes
#pragma unroll
    for (int mtl = 0; mtl < 2; ++mtl) {
      const int mt = wv * 2 + mtl;
      short8 Ar = xf[mtl][0], Ai = xf[mtl][1];
#pragma unroll
      for (int nt = 0; nt < 2; ++nt) {
        f32x4 zr = {0.f, 0.f, 0.f, 0.f}, zi = {0.f, 0.f, 0.f, 0.f};
        zr = mfma16(Ar, bfrag[0][nt], zr);
        zr = mfma16(Ar, bfrag[1][nt], zr);
        zr = mfma16(Ai, bfrag[4][nt], zr);
        zr = mfma16(Ai, bfrag[5][nt], zr);
        zi = mfma16(Ar, bfrag[2][nt], zi);
        zi = mfma16(Ar, bfrag[3][nt], zi);
        zi = mfma16(Ai, bfrag[0][nt], zi);
        zi = mfma16(Ai, bfrag[1][nt], zi);
#pragma unroll
        for (int j = 0; j < 4; ++j) {
          int mrow = mt * 16 + ((lane >> 4) << 2) + j; // c*2+t
          int c = mrow >> 1, t = mrow & 1;
          int v = nt * 16 + (lane & 15);
          int pos2 = t * 32 + v;
          uint32_t pk = (uint32_t)f2bf(zr[j]) | ((uint32_t)f2bf(zi[j]) << 16);
          *(uint32_t*)&zbuf[SWZ(pos2, 2 * c)] = pk;
        }
      }
    }
    __syncthreads();

    // phase B: y += Wd * zbuf  (Wd a-frags direct from global, b-frags hoisted)
    const ushort_t* wb = wfrag + (size_t)i * 16384;
#pragma unroll
    for (int ks = 0; ks < 4; ++ks) {
      short8 af0 = *(const short8*)&wb[(((wv * 2 + 0) * 4 + ks) * 64 + lane) * 8];
      short8 af1 = *(const short8*)&wb[(((wv * 2 + 1) * 4 + ks) * 64 + lane) * 8];
#pragma unroll
      for (int nt = 0; nt < 4; ++nt) {
        int brow = nt * 16 + (lane & 15);
        short8 bf = *(const short8*)&zbuf[SWZ(brow, ks * 32 + ((lane >> 4) << 3))];
        acc[0][nt] = mfma16(af0, bf, acc[0][nt]);
        acc[1][nt] = mfma16(af1, bf, acc[1][nt]);
      }
    }
    __syncthreads(); // WAR: next i's phase A rewrites zbuf
  }

  // epilogue: bias, write y, block-local BN partials (deterministic)
#pragma unroll
  for (int mtl = 0; mtl < 2; ++mtl) {
#pragma unroll
    for (int j = 0; j < 4; ++j) {
      int row = (wv * 2 + mtl) * 16 + ((lane >> 4) << 2) + j;
      float bias = bd[row] + bd[128 + row] + bd[256 + row];
      float s = 0.f, q = 0.f;
#pragma unroll
      for (int nt = 0; nt < 4; ++nt) {
        int pos2 = nt * 16 + (lane & 15);
        int t = pos2 >> 5, v = pos2 & 31;
        float val = acc[mtl][nt][j] + bias;
        if (v < VV) {
          int ri = row >> 6, o = row & 63;
          out[(size_t)ri * PLANE + (size_t)n * CTV + o * TV + (tc * 2 + t) * VV + v] = val;
          s += val; q += val * val;
        }
      }
#pragma unroll
      for (int d = 1; d < 16; d <<= 1) { s += __shfl_xor(s, d); q += __shfl_xor(q, d); }
      if ((lane & 15) == 0) { stats[row * 2] = s; stats[row * 2 + 1] = q; }
    }
  }
  __syncthreads();
  if (tid < 128) {
    size_t b = (size_t)(n * 128 + tc);
    bnpart[(b * 128 + tid) * 2]     = stats[tid * 2];
    bnpart[(b * 128 + tid) * 2 + 1] = stats[tid * 2 + 1];
  }
}

// ---------------------------------------------------------------------------
// K4: reduce bnpart -> per-channel coeff (mu_r, mu_i, scale, shift)
// ---------------------------------------------------------------------------
__global__ __launch_bounds__(256) void k4_stats(
    const float* __restrict__ bnpart, const float* __restrict__ bnw,
    const float* __restrict__ bnb, float* __restrict__ coeff)
{
  const int o = blockIdx.x, tid = threadIdx.x;
  float sr = 0.f, qr = 0.f, si = 0.f, qi = 0.f;
  for (int b = tid; b < 4096; b += 256) {
    const float* p = bnpart + ((size_t)b * 128 + o) * 2;
    sr += p[0]; qr += p[1];
    const float* p2 = bnpart + ((size_t)b * 128 + 64 + o) * 2;
    si += p2[0]; qi += p2[1];
  }
#pragma unroll
  for (int d = 1; d < 64; d <<= 1) {
    sr += __shfl_xor(sr, d); qr += __shfl_xor(qr, d);
    si += __shfl_xor(si, d); qi += __shfl_xor(qi, d);
  }
  __shared__ float red[4][4];
  int lane = tid & 63, wv = tid >> 6;
  if (lane == 0) { red[wv][0] = sr; red[wv][1] = qr; red[wv][2] = si; red[wv][3] = qi; }
  __syncthreads();
  if (tid == 0) {
    sr = red[0][0] + red[1][0] + red[2][0] + red[3][0];
    qr = red[0][1] + red[1][1] + red[2][1] + red[3][1];
    si = red[0][2] + red[1][2] + red[2][2] + red[3][2];
    qi = red[0][3] + red[1][3] + red[2][3] + red[3][3];
    const float invM = 1.f / (float)((size_t)NN * TTOT * VV);
    float mur = sr * invM, mui = si * invM;
    float var = (qr + qi) * invM - mur * mur - mui * mui;
    float inv = rsqrtf(var + 1e-5f);
    coeff[o * 4 + 0] = mur; coeff[o * 4 + 1] = mui;
    coeff[o * 4 + 2] = inv * bnw[o]; coeff[o * 4 + 3] = bnb[o];
  }
}

// ---------------------------------------------------------------------------
// K5: yn = (y - mu)*scale + shift + x  (in-place on d_out, vectorized)
// ---------------------------------------------------------------------------
__global__ __launch_bounds__(256) void k5_norm(
    const float* __restrict__ xr, const float* __restrict__ xi,
    const float* __restrict__ coeff, float* __restrict__ out)
{
  size_t idx0 = ((size_t)blockIdx.x * 256 + threadIdx.x) * 4;
  size_t stride = (size_t)gridDim.x * 256 * 4;
  for (size_t e = idx0; e < PLANE; e += stride) {
    int o = (int)((e / TV) & 63);
    float4 cf = *(const float4*)&coeff[o * 4];
    float4 yr = *(float4*)&out[e];
    float4 yi = *(float4*)&out[PLANE + e];
    float4 vr = *(const float4*)&xr[e];
    float4 vi = *(const float4*)&xi[e];
    yr.x = (yr.x - cf.x) * cf.z + cf.w + vr.x;
    yr.y = (yr.y - cf.x) * cf.z + cf.w + vr.y;
    yr.z = (yr.z - cf.x) * cf.z + cf.w + vr.z;
    yr.w = (yr.w - cf.x) * cf.z + cf.w + vr.w;
    yi.x = (yi.x - cf.y) * cf.z + vi.x;
    yi.y = (yi.y - cf.y) * cf.z + vi.y;
    yi.z = (yi.z - cf.y) * cf.z + vi.z;
    yi.w = (yi.w - cf.y) * cf.z + vi.w;
    *(float4*)&out[e] = yr;
    *(float4*)&out[PLANE + e] = yi;
  }
}

// ---------------------------------------------------------------------------
extern "C" void kernel_launch(void* const* d_in, const int* in_sizes, int n_in,
                              void* d_out, int out_size, void* d_ws, size_t ws_size,
                              hipStream_t stream) {
  const float* xr  = (const float*)d_in[0];
  const float* xi  = (const float*)d_in[1];
  const float* Aw  = (const float*)d_in[2];
  const float* PA  = (const float*)d_in[3];
  const float* Wa  = (const float*)d_in[4];
  const float* ba  = (const float*)d_in[5];
  const float* Wb  = (const float*)d_in[6];
  const float* bb  = (const float*)d_in[7];
  const float* Wd  = (const float*)d_in[8];
  const float* bd  = (const float*)d_in[9];
  const float* bnw = (const float*)d_in[10];
  const float* bnb = (const float*)d_in[11];
  float* out = (float*)d_out;
  float* ws = (float*)d_ws;

  // ws layout (floats). bnpart aliases Spart: Spart is dead once k2 completes,
  // and k3 (the bnpart writer) launches after k2 on the same stream.
  float*    Spart  = ws;                         // 7,680,000 floats
  float*    bnpart = ws;                         // 1,048,576 floats (alias)
  ushort_t* sfrag  = (ushort_t*)(ws + 7680000);  // 589,824 ushorts
  ushort_t* wfrag  = (ushort_t*)(ws + 7974912);  // 49,152 ushorts
  float*    coeff  = ws + 7999488;               // 256 floats
  // total: 7,999,744 floats = 32.0 MB

  k0_wfrag<<<NS, 256, 0, stream>>>(Wd, wfrag);
  k1_spart<<<dim3(64, NN), 256, 0, stream>>>(xr, xi, Wa, ba, Wb, bb, Spart);
  k2_softmax<<<dim3(NS, NN), 256, 0, stream>>>(Spart, Aw, PA, sfrag);
  k3_y<<<dim3(128, NN), 256, 0, stream>>>(xr, xi, sfrag, wfrag, bd, out, bnpart);
  k4_stats<<<64, 256, 0, stream>>>(bnpart, bnw, bnb, coeff);
  k5_norm<<<6400, 256, 0, stream>>>(xr, xi, coeff, out);
}

// Round 4
// 292.854 us; speedup vs baseline: 6.0542x; 1.0161x over previous
//
#include <hip/hip_runtime.h>
#include <hip/hip_bf16.h>
#include <stdint.h>

#define NN 32
#define CC 64
#define TTOT 256
#define VV 25
#define NS 3
constexpr int TV  = TTOT * VV;            // 6400
constexpr int CTV = CC * TV;              // 409600
constexpr size_t PLANE = (size_t)NN * CTV; // 13107200

typedef unsigned short ushort_t;
using short8 = __attribute__((ext_vector_type(8))) short;
using f32x4  = __attribute__((ext_vector_type(4))) float;

static __device__ __forceinline__ ushort_t f2bf(float f) {
  union { float f; uint32_t u; } v; v.f = f;
  return (ushort_t)((v.u + 0x7FFFu + ((v.u >> 16) & 1u)) >> 16);
}
static __device__ __forceinline__ float bf2f(ushort_t h) {
  union { uint32_t u; float f; } v; v.u = ((uint32_t)h) << 16;
  return v.f;
}
// element offset into a [row][128] bf16 tile, XOR-swizzled (byte ^= (row&7)<<4)
static __device__ __forceinline__ int SWZ(int row, int k) {
  return ((row << 7) + k) ^ ((row & 7) << 3);
}
static __device__ __forceinline__ f32x4 mfma16(short8 a, short8 b, f32x4 c) {
  return __builtin_amdgcn_mfma_f32_16x16x32_bf16(a, b, c, 0, 0, 0);
}

// ---------------------------------------------------------------------------
// K0: pre-fragment Wd into bf16, column-permuted to interleaved k'=2c+comp.
// ---------------------------------------------------------------------------
__global__ __launch_bounds__(256) void k0_wfrag(
    const float* __restrict__ Wd, ushort_t* __restrict__ wfrag)
{
  const int i = blockIdx.x;
  for (int e = threadIdx.x; e < 16384; e += 256) {
    int mt = e >> 11;
    int ks = (e >> 9) & 3;
    int l  = (e >> 3) & 63;
    int j  = e & 7;
    int r  = mt * 16 + (l & 15);
    int kp = ks * 32 + ((l >> 4) << 3) + j;   // interleaved channel index
    int c = kp >> 1, comp = kp & 1;
    wfrag[(size_t)i * 16384 + e] = f2bf(Wd[(size_t)i * 16384 + r * 128 + comp * 64 + c]);
  }
}

// ---------------------------------------------------------------------------
// K1: per (n, tc) with 4 t's: conv (MFMA) -> Ga/Gb transposed in LDS ->
//     Gram via MFMA (25x25, K=64). Spart[3][32][64][25][25][2]
// ---------------------------------------------------------------------------
__global__ __launch_bounds__(256) void k1_spart(
    const float* __restrict__ xr, const float* __restrict__ xi,
    const float* __restrict__ Wa, const float* __restrict__ ba,
    const float* __restrict__ Wb, const float* __restrict__ bb,
    float* __restrict__ Spart)
{
  const int tc = blockIdx.x, n = blockIdx.y;
  const int tid = threadIdx.x, lane = tid & 63, wv = tid >> 6;
  __shared__ alignas(16) ushort_t zc[128 * 128]; // [pos2=t*32+v][c] swizzled
  __shared__ alignas(16) ushort_t wl[64 * 128];  // [row][c] swizzled
  __shared__ alignas(16) ushort_t Ga[32 * 128];  // [u][k: ar 0-63, ai 64-127] swz
  __shared__ alignas(16) ushort_t Gb[32 * 128];  // [v][k: br 0-63, bi 64-127] swz

  // stage zc: float4 loads (100 contiguous floats per c = 25 float4)
  for (int e4 = tid; e4 < 128 * 25; e4 += 256) {
    int c = e4 / 25, q = e4 % 25;
    const float* src = (c < 64) ? xr : xi;
    float4 w = *(const float4*)&src[(size_t)n * CTV + (c & 63) * TV + tc * 100 + q * 4];
#pragma unroll
    for (int jj = 0; jj < 4; ++jj) {
      int g = q * 4 + jj, t = g / 25, v = g - t * 25;
      zc[SWZ(t * 32 + v, c)] = f2bf(((const float*)&w)[jj]);
    }
  }
  // zero-pad v=25..31
  for (int e = tid; e < 28 * 128; e += 256) {
    int r7 = e >> 7, c = e & 127;
    int t = r7 / 7, vv = 25 + r7 % 7;
    zc[SWZ(t * 32 + vv, c)] = 0;
  }

  const int mu = wv >> 1, nv = wv & 1;

  for (int i = 0; i < NS; ++i) {
    __syncthreads(); // zc ready (i==0); WAR on wl/Ga/Gb vs previous iter

    // stage weights (float4): rows 0..31 = Wa[i], 32..63 = Wb[i]
    for (int e4 = tid; e4 < 64 * 32; e4 += 256) {
      int r = e4 >> 5, c4 = (e4 & 31) * 4;
      const float* w = (r < 32) ? (Wa + (size_t)(i * 32 + r) * 128)
                                : (Wb + (size_t)(i * 32 + (r - 32)) * 128);
      float4 wf = *(const float4*)&w[c4];
#pragma unroll
      for (int jj = 0; jj < 4; ++jj) wl[SWZ(r, c4 + jj)] = f2bf(((const float*)&wf)[jj]);
    }
    __syncthreads();

    // conv: wave wv owns output rows [wv*16, wv*16+16) -> all one component
    {
      const int mt = wv;
      const int arow = mt * 16 + (lane & 15);
      short8 afr[4];
#pragma unroll
      for (int ks = 0; ks < 4; ++ks)
        afr[ks] = *(const short8*)&wl[SWZ(arow, ks * 32 + ((lane >> 4) << 3))];
      float bias[4];
#pragma unroll
      for (int j = 0; j < 4; ++j) {
        int row = mt * 16 + ((lane >> 4) << 2) + j;
        bias[j] = (row < 32) ? ba[i * 32 + row] : bb[i * 32 + (row - 32)];
      }
      const int comp = mt;               // 0=ar 1=ai 2=br 3=bi
      ushort_t* gbuf = (comp < 2) ? Ga : Gb;
      const int half = (comp & 1) * 64;
      for (int nt = 0; nt < 8; ++nt) {
        f32x4 acc = {0.f, 0.f, 0.f, 0.f};
        const int brow = nt * 16 + (lane & 15);
#pragma unroll
        for (int ks = 0; ks < 4; ++ks) {
          short8 bfr = *(const short8*)&zc[SWZ(brow, ks * 32 + ((lane >> 4) << 3))];
          acc = mfma16(afr[ks], bfr, acc);
        }
#pragma unroll
        for (int j = 0; j < 4; ++j) {
          int it = ((lane >> 4) << 2) + j;       // row&15
          int pos2 = nt * 16 + (lane & 15);
          int t = pos2 >> 5, v = pos2 & 31;
          gbuf[SWZ(v, half + it * 4 + t)] = f2bf(acc[j] + bias[j]);
        }
      }
    }
    __syncthreads();

    // Gram via MFMA: wave (mu,nv) computes S[mu*16..+16)[nv*16..+16)
    {
      const int urow = mu * 16 + (lane & 15);
      const int vrow = nv * 16 + (lane & 15);
      f32x4 Prr = {0.f,0.f,0.f,0.f}, Pii = {0.f,0.f,0.f,0.f};
      f32x4 Pri = {0.f,0.f,0.f,0.f}, Pir = {0.f,0.f,0.f,0.f};
#pragma unroll
      for (int ks = 0; ks < 2; ++ks) {
        int ko = ks * 32 + ((lane >> 4) << 3);
        short8 arF = *(const short8*)&Ga[SWZ(urow, ko)];
        short8 aiF = *(const short8*)&Ga[SWZ(urow, 64 + ko)];
        short8 brF = *(const short8*)&Gb[SWZ(vrow, ko)];
        short8 biF = *(const short8*)&Gb[SWZ(vrow, 64 + ko)];
        Prr = mfma16(arF, brF, Prr);
        Pii = mfma16(aiF, biF, Pii);
        Pri = mfma16(arF, biF, Pri);
        Pir = mfma16(aiF, brF, Pir);
      }
#pragma unroll
      for (int j = 0; j < 4; ++j) {
        int u = mu * 16 + ((lane >> 4) << 2) + j;
        int v = nv * 16 + (lane & 15);
        if (u < VV && v < VV) {
          size_t idx = ((((size_t)i * NN + n) * 64 + tc) * 625 + u * 25 + v) * 2;
          Spart[idx]     = Prr[j] - Pii[j];
          Spart[idx + 1] = Pri[j] + Pir[j];
        }
      }
    }
  }
}

// ---------------------------------------------------------------------------
// K2: reduce Spart over tc, /4096, complex softmax over u, + (A+PA),
//     then emit packed bf16 hi/lo S-fragments in per-lane MFMA order.
// sfrag[i][n][m(6)][nt(2)][lane(64)][j(8)]  (m: Srh,Srl,Sih,Sil,-Sih,-Sil)
// ---------------------------------------------------------------------------
__global__ __launch_bounds__(256) void k2_softmax(
    const float* __restrict__ Spart, const float* __restrict__ Aw,
    const float* __restrict__ PA, ushort_t* __restrict__ sfrag)
{
  const int i = blockIdx.x, n = blockIdx.y, tid = threadIdx.x;
  __shared__ float ez[625 * 2];
  __shared__ float den[25 * 2];
  for (int e = tid; e < 625; e += 256) {
    float sr = 0.f, si = 0.f;
    const float* p = Spart + (((size_t)i * NN + n) * 64 * 625 + e) * 2;
    for (int tcb = 0; tcb < 64; ++tcb) { sr += p[0]; si += p[1]; p += 625 * 2; }
    sr *= (1.f / 4096.f); si *= (1.f / 4096.f);
    float m = expf(sr);
    ez[e * 2] = m * cosf(si);
    ez[e * 2 + 1] = m * sinf(si);
  }
  __syncthreads();
  if (tid < 25) {
    float dr = 0.f, di = 0.f;
    for (int u = 0; u < 25; ++u) { dr += ez[(u * 25 + tid) * 2]; di += ez[(u * 25 + tid) * 2 + 1]; }
    float inv = 1.f / (dr * dr + di * di);
    den[tid * 2] = dr * inv; den[tid * 2 + 1] = -di * inv; // conj(d)/|d|^2
  }
  __syncthreads();
  for (int e = tid; e < 625; e += 256) {
    int v = e % 25;
    float er = ez[e * 2], ei = ez[e * 2 + 1];
    float dr = den[v * 2], di = den[v * 2 + 1];
    float outr = er * dr - ei * di + Aw[i * 625 + e] + PA[i * 625 + e];
    float outi = er * di + ei * dr;
    ez[e * 2] = outr; ez[e * 2 + 1] = outi;   // finalize in place
  }
  __syncthreads();
  // pack fragments
  for (int e = tid; e < 768; e += 256) {
    int l = e & 63, nt = (e >> 6) & 1, m = e >> 7;
    int u0 = (l >> 4) << 3, v = nt * 16 + (l & 15);
    short8 pk;
#pragma unroll
    for (int j = 0; j < 8; ++j) {
      int u = u0 + j;
      float val = 0.f;
      if (u < VV && v < VV) {
        float sr_ = ez[(u * 25 + v) * 2], si_ = ez[(u * 25 + v) * 2 + 1];
        float base = (m < 2) ? sr_ : (m < 4) ? si_ : -si_;
        if (m & 1) { float hi = bf2f(f2bf(base)); val = base - hi; }
        else val = base;
      }
      pk[j] = (short)f2bf(val);
    }
    *(short8*)&sfrag[((size_t)(i * NN + n) * 768 + e) * 8] = pk;
  }
}

// ---------------------------------------------------------------------------
// K3: per (n, tc) with 2 t's. Single-barrier schedule:
//   phase A for all 3 i's (no barriers, pipelined) -> zbuf[3] (48KB)
//   one __syncthreads()
//   phase B for all 3 i's (96 MFMA + 48 ds_read_b128 uninterrupted)
// ---------------------------------------------------------------------------
__global__ __launch_bounds__(256) void k3_y(
    const float* __restrict__ xr, const float* __restrict__ xi,
    const ushort_t* __restrict__ sfrag, const ushort_t* __restrict__ wfrag,
    const float* __restrict__ bd, float* __restrict__ out,
    float* __restrict__ bnpart)
{
  const int tc = blockIdx.x, n = blockIdx.y;
  const int tid = threadIdx.x, lane = tid & 63, wv = tid >> 6;
  __shared__ alignas(16) ushort_t zbuf[3][64 * 128]; // [i][pos2][k'=2c+comp] swz
  __shared__ float stats[128 * 2];

  // x A-fragments, straight into registers (rows are 25-stride -> scalar loads)
  short8 xf[2][2]; // [mtl][comp]
  {
    const int u0 = (lane >> 4) << 3;
#pragma unroll
    for (int mtl = 0; mtl < 2; ++mtl) {
      int mrow = (wv * 2 + mtl) * 16 + (lane & 15);
      int c = mrow >> 1, t = mrow & 1;
#pragma unroll
      for (int comp = 0; comp < 2; ++comp) {
        const float* p = (comp ? xi : xr) + (size_t)n * CTV + c * TV + (tc * 2 + t) * VV;
        short8 f;
#pragma unroll
        for (int j = 0; j < 8; ++j) {
          int u = u0 + j;
          f[j] = (u < VV) ? (short)f2bf(p[u]) : (short)0;
        }
        xf[mtl][comp] = f;
      }
    }
  }

  // phase A: z = X2 * S for all i (complex via real MFMAs, hi+lo S)
#pragma unroll 1
  for (int i = 0; i < NS; ++i) {
    const ushort_t* sb = sfrag + (size_t)(i * NN + n) * 6144;
    short8 bfrag[6][2];
#pragma unroll
    for (int m = 0; m < 6; ++m)
#pragma unroll
      for (int nt = 0; nt < 2; ++nt)
        bfrag[m][nt] = *(const short8*)&sb[((m * 2 + nt) * 64 + lane) * 8];
#pragma unroll
    for (int mtl = 0; mtl < 2; ++mtl) {
      const int mt = wv * 2 + mtl;
      short8 Ar = xf[mtl][0], Ai = xf[mtl][1];
#pragma unroll
      for (int nt = 0; nt < 2; ++nt) {
        f32x4 zr = {0.f, 0.f, 0.f, 0.f}, zi = {0.f, 0.f, 0.f, 0.f};
        zr = mfma16(Ar, bfrag[0][nt], zr);
        zr = mfma16(Ar, bfrag[1][nt], zr);
        zr = mfma16(Ai, bfrag[4][nt], zr);
        zr = mfma16(Ai, bfrag[5][nt], zr);
        zi = mfma16(Ar, bfrag[2][nt], zi);
        zi = mfma16(Ar, bfrag[3][nt], zi);
        zi = mfma16(Ai, bfrag[0][nt], zi);
        zi = mfma16(Ai, bfrag[1][nt], zi);
#pragma unroll
        for (int j = 0; j < 4; ++j) {
          int mrow = mt * 16 + ((lane >> 4) << 2) + j; // c*2+t
          int c = mrow >> 1, t = mrow & 1;
          int v = nt * 16 + (lane & 15);
          int pos2 = t * 32 + v;
          uint32_t pk = (uint32_t)f2bf(zr[j]) | ((uint32_t)f2bf(zi[j]) << 16);
          *(uint32_t*)&zbuf[i][SWZ(pos2, 2 * c)] = pk;
        }
      }
    }
  }
  __syncthreads(); // the only barrier: zbuf fully written

  // phase B: y = sum_i Wd[i] * zbuf[i]   (effective K=384)
  f32x4 acc[2][4];
#pragma unroll
  for (int a = 0; a < 2; ++a)
#pragma unroll
    for (int b = 0; b < 4; ++b) acc[a][b] = {0.f, 0.f, 0.f, 0.f};

#pragma unroll 1
  for (int i = 0; i < NS; ++i) {
    const ushort_t* wb = wfrag + (size_t)i * 16384;
#pragma unroll
    for (int ks = 0; ks < 4; ++ks) {
      short8 af0 = *(const short8*)&wb[(((wv * 2 + 0) * 4 + ks) * 64 + lane) * 8];
      short8 af1 = *(const short8*)&wb[(((wv * 2 + 1) * 4 + ks) * 64 + lane) * 8];
#pragma unroll
      for (int nt = 0; nt < 4; ++nt) {
        int brow = nt * 16 + (lane & 15);
        short8 bf = *(const short8*)&zbuf[i][SWZ(brow, ks * 32 + ((lane >> 4) << 3))];
        acc[0][nt] = mfma16(af0, bf, acc[0][nt]);
        acc[1][nt] = mfma16(af1, bf, acc[1][nt]);
      }
    }
  }

  // epilogue: bias, write y, block-local BN partials (deterministic)
#pragma unroll
  for (int mtl = 0; mtl < 2; ++mtl) {
#pragma unroll
    for (int j = 0; j < 4; ++j) {
      int row = (wv * 2 + mtl) * 16 + ((lane >> 4) << 2) + j;
      float bias = bd[row] + bd[128 + row] + bd[256 + row];
      float s = 0.f, q = 0.f;
#pragma unroll
      for (int nt = 0; nt < 4; ++nt) {
        int pos2 = nt * 16 + (lane & 15);
        int t = pos2 >> 5, v = pos2 & 31;
        float val = acc[mtl][nt][j] + bias;
        if (v < VV) {
          int ri = row >> 6, o = row & 63;
          out[(size_t)ri * PLANE + (size_t)n * CTV + o * TV + (tc * 2 + t) * VV + v] = val;
          s += val; q += val * val;
        }
      }
#pragma unroll
      for (int d = 1; d < 16; d <<= 1) { s += __shfl_xor(s, d); q += __shfl_xor(q, d); }
      if ((lane & 15) == 0) { stats[row * 2] = s; stats[row * 2 + 1] = q; }
    }
  }
  __syncthreads();
  if (tid < 128) {
    size_t b = (size_t)(n * 128 + tc);
    bnpart[(b * 128 + tid) * 2]     = stats[tid * 2];
    bnpart[(b * 128 + tid) * 2 + 1] = stats[tid * 2 + 1];
  }
}

// ---------------------------------------------------------------------------
// K4: reduce bnpart -> per-channel coeff (mu_r, mu_i, scale, shift)
// ---------------------------------------------------------------------------
__global__ __launch_bounds__(256) void k4_stats(
    const float* __restrict__ bnpart, const float* __restrict__ bnw,
    const float* __restrict__ bnb, float* __restrict__ coeff)
{
  const int o = blockIdx.x, tid = threadIdx.x;
  float sr = 0.f, qr = 0.f, si = 0.f, qi = 0.f;
  for (int b = tid; b < 4096; b += 256) {
    const float* p = bnpart + ((size_t)b * 128 + o) * 2;
    sr += p[0]; qr += p[1];
    const float* p2 = bnpart + ((size_t)b * 128 + 64 + o) * 2;
    si += p2[0]; qi += p2[1];
  }
#pragma unroll
  for (int d = 1; d < 64; d <<= 1) {
    sr += __shfl_xor(sr, d); qr += __shfl_xor(qr, d);
    si += __shfl_xor(si, d); qi += __shfl_xor(qi, d);
  }
  __shared__ float red[4][4];
  int lane = tid & 63, wv = tid >> 6;
  if (lane == 0) { red[wv][0] = sr; red[wv][1] = qr; red[wv][2] = si; red[wv][3] = qi; }
  __syncthreads();
  if (tid == 0) {
    sr = red[0][0] + red[1][0] + red[2][0] + red[3][0];
    qr = red[0][1] + red[1][1] + red[2][1] + red[3][1];
    si = red[0][2] + red[1][2] + red[2][2] + red[3][2];
    qi = red[0][3] + red[1][3] + red[2][3] + red[3][3];
    const float invM = 1.f / (float)((size_t)NN * TTOT * VV);
    float mur = sr * invM, mui = si * invM;
    float var = (qr + qi) * invM - mur * mur - mui * mui;
    float inv = rsqrtf(var + 1e-5f);
    coeff[o * 4 + 0] = mur; coeff[o * 4 + 1] = mui;
    coeff[o * 4 + 2] = inv * bnw[o]; coeff[o * 4 + 3] = bnb[o];
  }
}

// ---------------------------------------------------------------------------
// K5: yn = (y - mu)*scale + shift + x  (in-place on d_out, vectorized)
// ---------------------------------------------------------------------------
__global__ __launch_bounds__(256) void k5_norm(
    const float* __restrict__ xr, const float* __restrict__ xi,
    const float* __restrict__ coeff, float* __restrict__ out)
{
  size_t idx0 = ((size_t)blockIdx.x * 256 + threadIdx.x) * 4;
  size_t stride = (size_t)gridDim.x * 256 * 4;
  for (size_t e = idx0; e < PLANE; e += stride) {
    int o = (int)((e / TV) & 63);
    float4 cf = *(const float4*)&coeff[o * 4];
    float4 yr = *(float4*)&out[e];
    float4 yi = *(float4*)&out[PLANE + e];
    float4 vr = *(const float4*)&xr[e];
    float4 vi = *(const float4*)&xi[e];
    yr.x = (yr.x - cf.x) * cf.z + cf.w + vr.x;
    yr.y = (yr.y - cf.x) * cf.z + cf.w + vr.y;
    yr.z = (yr.z - cf.x) * cf.z + cf.w + vr.z;
    yr.w = (yr.w - cf.x) * cf.z + cf.w + vr.w;
    yi.x = (yi.x - cf.y) * cf.z + vi.x;
    yi.y = (yi.y - cf.y) * cf.z + vi.y;
    yi.z = (yi.z - cf.y) * cf.z + vi.z;
    yi.w = (yi.w - cf.y) * cf.z + vi.w;
    *(float4*)&out[e] = yr;
    *(float4*)&out[PLANE + e] = yi;
  }
}

// ---------------------------------------------------------------------------
extern "C" void kernel_launch(void* const* d_in, const int* in_sizes, int n_in,
                              void* d_out, int out_size, void* d_ws, size_t ws_size,
                              hipStream_t stream) {
  const float* xr  = (const float*)d_in[0];
  const float* xi  = (const float*)d_in[1];
  const float* Aw  = (const float*)d_in[2];
  const float* PA  = (const float*)d_in[3];
  const float* Wa  = (const float*)d_in[4];
  const float* ba  = (const float*)d_in[5];
  const float* Wb  = (const float*)d_in[6];
  const float* bb  = (const float*)d_in[7];
  const float* Wd  = (const float*)d_in[8];
  const float* bd  = (const float*)d_in[9];
  const float* bnw = (const float*)d_in[10];
  const float* bnb = (const float*)d_in[11];
  float* out = (float*)d_out;
  float* ws = (float*)d_ws;

  // ws layout (floats). bnpart aliases Spart: Spart is dead once k2 completes,
  // and k3 (the bnpart writer) launches after k2 on the same stream.
  float*    Spart  = ws;                         // 7,680,000 floats
  float*    bnpart = ws;                         // 1,048,576 floats (alias)
  ushort_t* sfrag  = (ushort_t*)(ws + 7680000);  // 589,824 ushorts
  ushort_t* wfrag  = (ushort_t*)(ws + 7974912);  // 49,152 ushorts
  float*    coeff  = ws + 7999488;               // 256 floats
  // total: 7,999,744 floats = 32.0 MB

  k0_wfrag<<<NS, 256, 0, stream>>>(Wd, wfrag);
  k1_spart<<<dim3(64, NN), 256, 0, stream>>>(xr, xi, Wa, ba, Wb, bb, Spart);
  k2_softmax<<<dim3(NS, NN), 256, 0, stream>>>(Spart, Aw, PA, sfrag);
  k3_y<<<dim3(128, NN), 256, 0, stream>>>(xr, xi, sfrag, wfrag, bd, out, bnpart);
  k4_stats<<<64, 256, 0, stream>>>(bnpart, bnw, bnb, coeff);
  k5_norm<<<6400, 256, 0, stream>>>(xr, xi, coeff, out);
}

// Round 5
// 264.978 us; speedup vs baseline: 6.6911x; 1.1052x over previous
//
#include <hip/hip_runtime.h>
#include <hip/hip_bf16.h>
#include <stdint.h>

#define NN 32
#define CC 64
#define TTOT 256
#define VV 25
#define NS 3
constexpr int TV  = TTOT * VV;            // 6400
constexpr int CTV = CC * TV;              // 409600
constexpr size_t PLANE = (size_t)NN * CTV; // 13107200

typedef unsigned short ushort_t;
using short8 = __attribute__((ext_vector_type(8))) short;
using f32x4  = __attribute__((ext_vector_type(4))) float;

static __device__ __forceinline__ ushort_t f2bf(float f) {
  __hip_bfloat16 h = __float2bfloat16(f);   // RNE, compiles to v_cvt
  return reinterpret_cast<ushort_t&>(h);
}
static __device__ __forceinline__ float bf2f(ushort_t h) {
  union { uint32_t u; float f; } v; v.u = ((uint32_t)h) << 16;
  return v.f;
}
// element offset into a [row][128] bf16 tile, XOR-swizzled (byte ^= (row&7)<<4)
static __device__ __forceinline__ int SWZ(int row, int k) {
  return ((row << 7) + k) ^ ((row & 7) << 3);
}
static __device__ __forceinline__ f32x4 mfma16(short8 a, short8 b, f32x4 c) {
  return __builtin_amdgcn_mfma_f32_16x16x32_bf16(a, b, c, 0, 0, 0);
}

// ---------------------------------------------------------------------------
// K0: pre-fragment Wd (k'=2c+comp interleaved) and Wa/Wb (k=c planar) to bf16
// wfrag[i][mt(8)][ks(4)][lane(64)][j(8)];  wab[i][mt(4)][ks(4)][lane(64)][j(8)]
// ---------------------------------------------------------------------------
__global__ __launch_bounds__(256) void k0_wfrag(
    const float* __restrict__ Wd, const float* __restrict__ Wa,
    const float* __restrict__ Wb, ushort_t* __restrict__ wfrag,
    ushort_t* __restrict__ wab)
{
  const int i = blockIdx.x;
  for (int e = threadIdx.x; e < 16384; e += 256) {
    int mt = e >> 11, ks = (e >> 9) & 3, l = (e >> 3) & 63, j = e & 7;
    int r  = mt * 16 + (l & 15);
    int kp = ks * 32 + ((l >> 4) << 3) + j;   // interleaved channel index
    int c = kp >> 1, comp = kp & 1;
    wfrag[(size_t)i * 16384 + e] = f2bf(Wd[(size_t)i * 16384 + r * 128 + comp * 64 + c]);
  }
  for (int e = threadIdx.x; e < 8192; e += 256) {
    int mt = e >> 11, ks = (e >> 9) & 3, l = (e >> 3) & 63, j = e & 7;
    int r  = mt * 16 + (l & 15);                 // 0..63: 0-31 Wa, 32-63 Wb
    int kp = ks * 32 + ((l >> 4) << 3) + j;      // channel 0..127
    float v = (r < 32) ? Wa[((size_t)i * 32 + r) * 128 + kp]
                       : Wb[((size_t)i * 32 + (r - 32)) * 128 + kp];
    wab[(size_t)i * 8192 + e] = f2bf(v);
  }
}

// ---------------------------------------------------------------------------
// K1: per (n, tc) with 4 t's: conv (MFMA, weights from wab) -> Ga/Gb
//     (k-layout half + t*16 + it, b64 writes) -> Gram via MFMA.
// Spart[3][32][64][25][25][2]
// ---------------------------------------------------------------------------
__global__ __launch_bounds__(256) void k1_spart(
    const float* __restrict__ xr, const float* __restrict__ xi,
    const ushort_t* __restrict__ wab, const float* __restrict__ ba,
    const float* __restrict__ bb, float* __restrict__ Spart)
{
  const int tc = blockIdx.x, n = blockIdx.y;
  const int tid = threadIdx.x, lane = tid & 63, wv = tid >> 6;
  const int r16 = lane & 15, gw = lane >> 4;
  __shared__ alignas(16) ushort_t zc[128 * 128]; // [pos2=t*32+v][c] swizzled
  __shared__ alignas(16) ushort_t Ga[32 * 128];  // [u][k: half + t*16 + it] swz
  __shared__ alignas(16) ushort_t Gb[32 * 128];

  // stage zc: float4 loads (100 contiguous floats per c = 25 float4)
  for (int e4 = tid; e4 < 128 * 25; e4 += 256) {
    int c = e4 / 25, q = e4 % 25;
    const float* src = (c < 64) ? xr : xi;
    float4 w = *(const float4*)&src[(size_t)n * CTV + (c & 63) * TV + tc * 100 + q * 4];
#pragma unroll
    for (int jj = 0; jj < 4; ++jj) {
      int g = q * 4 + jj, t = g / 25, v = g - t * 25;
      zc[SWZ(t * 32 + v, c)] = f2bf(((const float*)&w)[jj]);
    }
  }
  // zero-pad v=25..31
  for (int e = tid; e < 28 * 128; e += 256) {
    int r7 = e >> 7, c = e & 127;
    int t = r7 / 7, vv = 25 + r7 % 7;
    zc[SWZ(t * 32 + vv, c)] = 0;
  }

  const int mu = wv >> 1, nv = wv & 1;

  for (int i = 0; i < NS; ++i) {
    __syncthreads(); // zc ready (i==0); WAR on Ga/Gb vs previous gram

    // conv: wave wv = component (0=ar 1=ai 2=br 3=bi)
    {
      short8 afr[4];
#pragma unroll
      for (int ks = 0; ks < 4; ++ks)
        afr[ks] = *(const short8*)&wab[((((size_t)i * 4 + wv) * 4 + ks) * 64 + lane) * 8];
      float bias[4];
#pragma unroll
      for (int j = 0; j < 4; ++j) {
        int row = wv * 16 + gw * 4 + j;
        bias[j] = (row < 32) ? ba[i * 32 + row] : bb[i * 32 + (row - 32)];
      }
      ushort_t* gbuf = (wv < 2) ? Ga : Gb;
      const int half = (wv & 1) * 64;
      for (int nt = 0; nt < 8; ++nt) {
        f32x4 acc = {0.f, 0.f, 0.f, 0.f};
        const int brow = nt * 16 + r16;
#pragma unroll
        for (int ks = 0; ks < 4; ++ks) {
          short8 bfr = *(const short8*)&zc[SWZ(brow, ks * 32 + gw * 8)];
          acc = mfma16(afr[ks], bfr, acc);
        }
        int pos2 = nt * 16 + r16;
        int t = pos2 >> 5, v = pos2 & 31;
        int k0w = half + t * 16 + gw * 4;     // it = gw*4+j contiguous
        uint32_t w0 = (uint32_t)f2bf(acc[0] + bias[0]) | ((uint32_t)f2bf(acc[1] + bias[1]) << 16);
        uint32_t w1 = (uint32_t)f2bf(acc[2] + bias[2]) | ((uint32_t)f2bf(acc[3] + bias[3]) << 16);
        uint2 pk; pk.x = w0; pk.y = w1;
        *(uint2*)&gbuf[SWZ(v, k0w)] = pk;
      }
    }
    __syncthreads();

    // Gram via MFMA: wave (mu,nv) computes S[mu*16..+16)[nv*16..+16)
    {
      const int urow = mu * 16 + r16;
      const int vrow = nv * 16 + r16;
      f32x4 Prr = {0.f,0.f,0.f,0.f}, Pii = {0.f,0.f,0.f,0.f};
      f32x4 Pri = {0.f,0.f,0.f,0.f}, Pir = {0.f,0.f,0.f,0.f};
#pragma unroll
      for (int ks = 0; ks < 2; ++ks) {
        int ko = ks * 32 + gw * 8;
        short8 arF = *(const short8*)&Ga[SWZ(urow, ko)];
        short8 aiF = *(const short8*)&Ga[SWZ(urow, 64 + ko)];
        short8 brF = *(const short8*)&Gb[SWZ(vrow, ko)];
        short8 biF = *(const short8*)&Gb[SWZ(vrow, 64 + ko)];
        Prr = mfma16(arF, brF, Prr);
        Pii = mfma16(aiF, biF, Pii);
        Pri = mfma16(arF, biF, Pri);
        Pir = mfma16(aiF, brF, Pir);
      }
#pragma unroll
      for (int j = 0; j < 4; ++j) {
        int u = mu * 16 + gw * 4 + j;
        int v = nv * 16 + r16;
        if (u < VV && v < VV) {
          size_t idx = ((((size_t)i * NN + n) * 64 + tc) * 625 + u * 25 + v) * 2;
          Spart[idx]     = Prr[j] - Pii[j];
          Spart[idx + 1] = Pri[j] + Pir[j];
        }
      }
    }
  }
}

// ---------------------------------------------------------------------------
// K2: reduce Spart over tc, /4096, complex softmax over u, + (A+PA),
//     then emit packed bf16 hi/lo S-fragments in per-lane MFMA order.
// sfrag[i][n][m(6)][nt(2)][lane(64)][j(8)]  (m: Srh,Srl,Sih,Sil,-Sih,-Sil)
// ---------------------------------------------------------------------------
__global__ __launch_bounds__(256) void k2_softmax(
    const float* __restrict__ Spart, const float* __restrict__ Aw,
    const float* __restrict__ PA, ushort_t* __restrict__ sfrag)
{
  const int i = blockIdx.x, n = blockIdx.y, tid = threadIdx.x;
  __shared__ float ez[625 * 2];
  __shared__ float den[25 * 2];
  for (int e = tid; e < 625; e += 256) {
    float sr = 0.f, si = 0.f;
    const float* p = Spart + (((size_t)i * NN + n) * 64 * 625 + e) * 2;
    for (int tcb = 0; tcb < 64; ++tcb) { sr += p[0]; si += p[1]; p += 625 * 2; }
    sr *= (1.f / 4096.f); si *= (1.f / 4096.f);
    float m = expf(sr);
    ez[e * 2] = m * cosf(si);
    ez[e * 2 + 1] = m * sinf(si);
  }
  __syncthreads();
  if (tid < 25) {
    float dr = 0.f, di = 0.f;
    for (int u = 0; u < 25; ++u) { dr += ez[(u * 25 + tid) * 2]; di += ez[(u * 25 + tid) * 2 + 1]; }
    float inv = 1.f / (dr * dr + di * di);
    den[tid * 2] = dr * inv; den[tid * 2 + 1] = -di * inv; // conj(d)/|d|^2
  }
  __syncthreads();
  for (int e = tid; e < 625; e += 256) {
    int v = e % 25;
    float er = ez[e * 2], ei = ez[e * 2 + 1];
    float dr = den[v * 2], di = den[v * 2 + 1];
    float outr = er * dr - ei * di + Aw[i * 625 + e] + PA[i * 625 + e];
    float outi = er * di + ei * dr;
    ez[e * 2] = outr; ez[e * 2 + 1] = outi;   // finalize in place
  }
  __syncthreads();
  // pack fragments
  for (int e = tid; e < 768; e += 256) {
    int l = e & 63, nt = (e >> 6) & 1, m = e >> 7;
    int u0 = (l >> 4) << 3, v = nt * 16 + (l & 15);
    short8 pk;
#pragma unroll
    for (int j = 0; j < 8; ++j) {
      int u = u0 + j;
      float val = 0.f;
      if (u < VV && v < VV) {
        float sr_ = ez[(u * 25 + v) * 2], si_ = ez[(u * 25 + v) * 2 + 1];
        float base = (m < 2) ? sr_ : (m < 4) ? si_ : -si_;
        if (m & 1) { float hi = bf2f(f2bf(base)); val = base - hi; }
        else val = base;
      }
      pk[j] = (short)f2bf(val);
    }
    *(short8*)&sfrag[((size_t)(i * NN + n) * 768 + e) * 8] = pk;
  }
}

// ---------------------------------------------------------------------------
// K3: per (n, tcc) with 4 t's, 512 threads (8 waves: tp = wv>>2, mq = wv&3).
// Planar M-rows (mrow = t01*64 + c): phase-A writes are single b128 stores.
// zbuf[2 tp][64 pos2][64 words], word c = (zr,zi) packed; k' = 2c+comp.
// ---------------------------------------------------------------------------
__global__ __launch_bounds__(512) void k3_y(
    const float* __restrict__ xr, const float* __restrict__ xi,
    const ushort_t* __restrict__ sfrag, const ushort_t* __restrict__ wfrag,
    const float* __restrict__ bd, float* __restrict__ out,
    float* __restrict__ bnpart)
{
  const int tcc = blockIdx.x, n = blockIdx.y;
  const int tid = threadIdx.x, lane = tid & 63, wv = tid >> 6;
  const int tp = wv >> 2, mq = wv & 3;
  const int r16 = lane & 15, gw = lane >> 4;
  __shared__ alignas(16) ushort_t zbuf[2][64 * 128]; // [tp][pos2][2c+comp] swz
  __shared__ float stats[2][128][2];

  // x A-fragments (planar rows): mrow = mt*16+r16, c = mrow&63, t01 = mrow>>6
  short8 xf[2][2]; // [mtl][comp]
#pragma unroll
  for (int mtl = 0; mtl < 2; ++mtl) {
    int mt = mq * 2 + mtl;
    int mrow = mt * 16 + r16;
    int c = mrow & 63, t01 = mrow >> 6;
    int t = tcc * 4 + tp * 2 + t01;
#pragma unroll
    for (int comp = 0; comp < 2; ++comp) {
      const float* p = (comp ? xi : xr) + (size_t)n * CTV + c * TV + t * VV;
      short8 f;
#pragma unroll
      for (int j = 0; j < 8; ++j) {
        int u = gw * 8 + j;
        f[j] = (u < VV) ? (short)f2bf(p[u]) : (short)0;
      }
      xf[mtl][comp] = f;
    }
  }

  f32x4 acc[2][4];
#pragma unroll
  for (int a = 0; a < 2; ++a)
#pragma unroll
    for (int b = 0; b < 4; ++b) acc[a][b] = {0.f, 0.f, 0.f, 0.f};

#pragma unroll 1
  for (int i = 0; i < NS; ++i) {
    // S fragments (same for every wave): 12 coalesced 16B loads, L2-hot
    const ushort_t* sb = sfrag + (size_t)(i * NN + n) * 6144;
    short8 bfrag[6][2];
#pragma unroll
    for (int m = 0; m < 6; ++m)
#pragma unroll
      for (int nt = 0; nt < 2; ++nt)
        bfrag[m][nt] = *(const short8*)&sb[((m * 2 + nt) * 64 + lane) * 8];

    __syncthreads(); // WAR: previous phase B done with zbuf

    // phase A: z = X2 * S (complex via real MFMAs, hi+lo S); b128 stores
#pragma unroll
    for (int mtl = 0; mtl < 2; ++mtl) {
      const int mt = mq * 2 + mtl;
      const int t01 = mt >> 2;
      const int cbase = (mt & 3) * 16 + gw * 4;
      short8 Ar = xf[mtl][0], Ai = xf[mtl][1];
#pragma unroll
      for (int nt = 0; nt < 2; ++nt) {
        f32x4 zr = {0.f, 0.f, 0.f, 0.f}, zi = {0.f, 0.f, 0.f, 0.f};
        zr = mfma16(Ar, bfrag[0][nt], zr);
        zr = mfma16(Ar, bfrag[1][nt], zr);
        zr = mfma16(Ai, bfrag[4][nt], zr);
        zr = mfma16(Ai, bfrag[5][nt], zr);
        zi = mfma16(Ar, bfrag[2][nt], zi);
        zi = mfma16(Ar, bfrag[3][nt], zi);
        zi = mfma16(Ai, bfrag[0][nt], zi);
        zi = mfma16(Ai, bfrag[1][nt], zi);
        int pos2 = t01 * 32 + nt * 16 + r16;
        short8 pk;
#pragma unroll
        for (int j = 0; j < 4; ++j) {
          pk[2 * j]     = (short)f2bf(zr[j]);
          pk[2 * j + 1] = (short)f2bf(zi[j]);
        }
        *(short8*)&zbuf[tp][SWZ(pos2, cbase * 2)] = pk;
      }
    }
    __syncthreads();

    // phase B: y += Wd * zbuf[tp]
    const ushort_t* wb = wfrag + (size_t)i * 16384;
#pragma unroll
    for (int ks = 0; ks < 4; ++ks) {
      short8 af0 = *(const short8*)&wb[(((mq * 2 + 0) * 4 + ks) * 64 + lane) * 8];
      short8 af1 = *(const short8*)&wb[(((mq * 2 + 1) * 4 + ks) * 64 + lane) * 8];
#pragma unroll
      for (int nt = 0; nt < 4; ++nt) {
        int brow = nt * 16 + r16;
        short8 bf = *(const short8*)&zbuf[tp][SWZ(brow, ks * 32 + gw * 8)];
        acc[0][nt] = mfma16(af0, bf, acc[0][nt]);
        acc[1][nt] = mfma16(af1, bf, acc[1][nt]);
      }
    }
  }

  // epilogue: bias, write y (wave's tp t-pair), per-tp BN partials
#pragma unroll
  for (int mtl = 0; mtl < 2; ++mtl) {
#pragma unroll
    for (int j = 0; j < 4; ++j) {
      int row = (mq * 2 + mtl) * 16 + gw * 4 + j;
      float bias = bd[row] + bd[128 + row] + bd[256 + row];
      float s = 0.f, q = 0.f;
#pragma unroll
      for (int nt = 0; nt < 4; ++nt) {
        int pos2 = nt * 16 + r16;
        int t01 = pos2 >> 5, v = pos2 & 31;
        float val = acc[mtl][nt][j] + bias;
        if (v < VV) {
          int ri = row >> 6, o = row & 63;
          int t = tcc * 4 + tp * 2 + t01;
          out[(size_t)ri * PLANE + (size_t)n * CTV + o * TV + t * VV + v] = val;
          s += val; q += val * val;
        }
      }
#pragma unroll
      for (int d = 1; d < 16; d <<= 1) { s += __shfl_xor(s, d); q += __shfl_xor(q, d); }
      if (r16 == 0) { stats[tp][row][0] = s; stats[tp][row][1] = q; }
    }
  }
  __syncthreads();
  if (tid < 128) {
    size_t b = (size_t)(n * 64 + tcc);
    bnpart[(b * 128 + tid) * 2]     = stats[0][tid][0] + stats[1][tid][0];
    bnpart[(b * 128 + tid) * 2 + 1] = stats[0][tid][1] + stats[1][tid][1];
  }
}

// ---------------------------------------------------------------------------
// K4: reduce bnpart (2048 partials) -> per-channel coeff
// ---------------------------------------------------------------------------
__global__ __launch_bounds__(256) void k4_stats(
    const float* __restrict__ bnpart, const float* __restrict__ bnw,
    const float* __restrict__ bnb, float* __restrict__ coeff)
{
  const int o = blockIdx.x, tid = threadIdx.x;
  float sr = 0.f, qr = 0.f, si = 0.f, qi = 0.f;
  for (int b = tid; b < 2048; b += 256) {
    const float* p = bnpart + ((size_t)b * 128 + o) * 2;
    sr += p[0]; qr += p[1];
    const float* p2 = bnpart + ((size_t)b * 128 + 64 + o) * 2;
    si += p2[0]; qi += p2[1];
  }
#pragma unroll
  for (int d = 1; d < 64; d <<= 1) {
    sr += __shfl_xor(sr, d); qr += __shfl_xor(qr, d);
    si += __shfl_xor(si, d); qi += __shfl_xor(qi, d);
  }
  __shared__ float red[4][4];
  int lane = tid & 63, wv = tid >> 6;
  if (lane == 0) { red[wv][0] = sr; red[wv][1] = qr; red[wv][2] = si; red[wv][3] = qi; }
  __syncthreads();
  if (tid == 0) {
    sr = red[0][0] + red[1][0] + red[2][0] + red[3][0];
    qr = red[0][1] + red[1][1] + red[2][1] + red[3][1];
    si = red[0][2] + red[1][2] + red[2][2] + red[3][2];
    qi = red[0][3] + red[1][3] + red[2][3] + red[3][3];
    const float invM = 1.f / (float)((size_t)NN * TTOT * VV);
    float mur = sr * invM, mui = si * invM;
    float var = (qr + qi) * invM - mur * mur - mui * mui;
    float inv = rsqrtf(var + 1e-5f);
    coeff[o * 4 + 0] = mur; coeff[o * 4 + 1] = mui;
    coeff[o * 4 + 2] = inv * bnw[o]; coeff[o * 4 + 3] = bnb[o];
  }
}

// ---------------------------------------------------------------------------
// K5: yn = (y - mu)*scale + shift + x  (in-place on d_out, vectorized)
// ---------------------------------------------------------------------------
__global__ __launch_bounds__(256) void k5_norm(
    const float* __restrict__ xr, const float* __restrict__ xi,
    const float* __restrict__ coeff, float* __restrict__ out)
{
  size_t idx0 = ((size_t)blockIdx.x * 256 + threadIdx.x) * 4;
  size_t stride = (size_t)gridDim.x * 256 * 4;
  for (size_t e = idx0; e < PLANE; e += stride) {
    int o = (int)((e / TV) & 63);
    float4 cf = *(const float4*)&coeff[o * 4];
    float4 yr = *(float4*)&out[e];
    float4 yi = *(float4*)&out[PLANE + e];
    float4 vr = *(const float4*)&xr[e];
    float4 vi = *(const float4*)&xi[e];
    yr.x = (yr.x - cf.x) * cf.z + cf.w + vr.x;
    yr.y = (yr.y - cf.x) * cf.z + cf.w + vr.y;
    yr.z = (yr.z - cf.x) * cf.z + cf.w + vr.z;
    yr.w = (yr.w - cf.x) * cf.z + cf.w + vr.w;
    yi.x = (yi.x - cf.y) * cf.z + vi.x;
    yi.y = (yi.y - cf.y) * cf.z + vi.y;
    yi.z = (yi.z - cf.y) * cf.z + vi.z;
    yi.w = (yi.w - cf.y) * cf.z + vi.w;
    *(float4*)&out[e] = yr;
    *(float4*)&out[PLANE + e] = yi;
  }
}

// ---------------------------------------------------------------------------
extern "C" void kernel_launch(void* const* d_in, const int* in_sizes, int n_in,
                              void* d_out, int out_size, void* d_ws, size_t ws_size,
                              hipStream_t stream) {
  const float* xr  = (const float*)d_in[0];
  const float* xi  = (const float*)d_in[1];
  const float* Aw  = (const float*)d_in[2];
  const float* PA  = (const float*)d_in[3];
  const float* Wa  = (const float*)d_in[4];
  const float* ba  = (const float*)d_in[5];
  const float* Wb  = (const float*)d_in[6];
  const float* bb  = (const float*)d_in[7];
  const float* Wd  = (const float*)d_in[8];
  const float* bd  = (const float*)d_in[9];
  const float* bnw = (const float*)d_in[10];
  const float* bnb = (const float*)d_in[11];
  float* out = (float*)d_out;
  float* ws = (float*)d_ws;

  // ws layout (floats). bnpart aliases Spart (Spart dead after k2).
  float*    Spart  = ws;                         // 7,680,000 floats
  float*    bnpart = ws;                         // 524,288 floats (alias)
  ushort_t* sfrag  = (ushort_t*)(ws + 7680000);  // 589,824 ushorts
  ushort_t* wfrag  = (ushort_t*)(ws + 7974912);  // 49,152 ushorts
  ushort_t* wab    = (ushort_t*)(ws + 7999488);  // 24,576 ushorts
  float*    coeff  = ws + 8011776;               // 256 floats
  // total ≈ 32.05 MB

  k0_wfrag<<<NS, 256, 0, stream>>>(Wd, Wa, Wb, wfrag, wab);
  k1_spart<<<dim3(64, NN), 256, 0, stream>>>(xr, xi, wab, ba, bb, Spart);
  k2_softmax<<<dim3(NS, NN), 256, 0, stream>>>(Spart, Aw, PA, sfrag);
  k3_y<<<dim3(64, NN), 512, 0, stream>>>(xr, xi, sfrag, wfrag, bd, out, bnpart);
  k4_stats<<<64, 256, 0, stream>>>(bnpart, bnw, bnb, coeff);
  k5_norm<<<6400, 256, 0, stream>>>(xr, xi, coeff, out);
}